// Round 7
// baseline (914.652 us; speedup 1.0000x reference)
//
#include <hip/hip_runtime.h>

typedef __bf16 bf16x8 __attribute__((ext_vector_type(8)));
typedef float  f32x4  __attribute__((ext_vector_type(4)));
typedef float  f32x16 __attribute__((ext_vector_type(16)));
typedef unsigned u32x2 __attribute__((ext_vector_type(2)));

#define MFMA16(a,b,c) __builtin_amdgcn_mfma_f32_16x16x32_bf16((a),(b),(c),0,0,0)
#define MFMA32(a,b,c) __builtin_amdgcn_mfma_f32_32x32x16_bf16((a),(b),(c),0,0,0)

constexpr int  HID  = 768;
constexpr long T    = 16384;          // NUM_SEQS * SEQ_LEN
constexpr long SZ   = T * HID;        // 12,582,912 elements
constexpr int  SEQ  = 2048;
constexpr int  NH   = 12;
constexpr int  HD   = 64;
constexpr int  WELE = HID * HID;      // 589,824

// Q pre-scale: (1/sqrt(64)) * log2(e)  -> softmax done in exp2 domain
constexpr float QSCALE = 0.125f * 1.4426950408889634f;
// log2(10000)/32 for RoPE inv_freq = 2^(-d * L10K32)
constexpr float L10K32 = 13.287712379549449f / 32.0f;

__device__ __forceinline__ unsigned pkbf(float a, float b) {
    union { __bf16 h[2]; unsigned u; } x;
    x.h[0] = (__bf16)a; x.h[1] = (__bf16)b; return x.u;
}

// async global->LDS, 16B per lane; LDS dest = uniform base + lane*16
__device__ __forceinline__ void gld16(const __bf16* g, __bf16* l) {
    __builtin_amdgcn_global_load_lds(
        (const __attribute__((address_space(1))) unsigned int*)g,
        (__attribute__((address_space(3))) unsigned int*)l, 16, 0, 0);
}

// ---------------------------------------------------------------------------
// Weight convert+transpose, LDS-tiled. Wt[n][k] = bf16(W[k][n]).
// ---------------------------------------------------------------------------
__global__ __launch_bounds__(256)
void wconv_kernel(const float* __restrict__ W0, __bf16* __restrict__ T0,
                  const float* __restrict__ W1, __bf16* __restrict__ T1,
                  const float* __restrict__ W2, __bf16* __restrict__ T2,
                  const float* __restrict__ W3, __bf16* __restrict__ T3) {
    const float* W; __bf16* Wt;
    switch (blockIdx.z) {
        case 0: W = W0; Wt = T0; break;
        case 1: W = W1; Wt = T1; break;
        case 2: W = W2; Wt = T2; break;
        default: W = W3; Wt = T3; break;
    }
    __shared__ float tile[64][65];
    int n0 = blockIdx.x * 64, k0 = blockIdx.y * 64;
    int c = threadIdx.x & 63, rr = threadIdx.x >> 6;
#pragma unroll
    for (int i = 0; i < 16; i++) {
        int r = i * 4 + rr;
        tile[r][c] = W[(long)(k0 + r) * HID + n0 + c];
    }
    __syncthreads();
#pragma unroll
    for (int i = 0; i < 16; i++) {
        int r = i * 4 + rr;
        Wt[(long)(n0 + r) * HID + k0 + c] = (__bf16)tile[c][r];
    }
}

// ---------------------------------------------------------------------------
// LayerNorm
// ---------------------------------------------------------------------------
__global__ __launch_bounds__(256)
void ln_kernel(const float* __restrict__ hs, const float* __restrict__ w,
               const float* __restrict__ b, __bf16* __restrict__ xbf) {
    int row = blockIdx.x, tid = threadIdx.x;
    const float* hr = hs + (long)row * HID;
    float v0 = hr[tid], v1 = hr[tid + 256], v2 = hr[tid + 512];
    float s  = v0 + v1 + v2;
    float s2 = v0 * v0 + v1 * v1 + v2 * v2;
#pragma unroll
    for (int off = 1; off < 64; off <<= 1) {
        s  += __shfl_xor(s, off);
        s2 += __shfl_xor(s2, off);
    }
    __shared__ float red[8];
    int wave = tid >> 6;
    if ((tid & 63) == 0) { red[wave] = s; red[4 + wave] = s2; }
    __syncthreads();
    s  = red[0] + red[1] + red[2] + red[3];
    s2 = red[4] + red[5] + red[6] + red[7];
    float mu   = s * (1.0f / HID);
    float var  = s2 * (1.0f / HID) - mu * mu;
    float rstd = rsqrtf(var + 1e-12f);
    long base = (long)row * HID;
    xbf[base + tid]       = (__bf16)((v0 - mu) * rstd * w[tid]       + b[tid]);
    xbf[base + tid + 256] = (__bf16)((v1 - mu) * rstd * w[tid + 256] + b[tid + 256]);
    xbf[base + tid + 512] = (__bf16)((v2 - mu) * rstd * w[tid + 512] + b[tid + 512]);
}

// ---------------------------------------------------------------------------
// GEMM, m97-style: C[M,N] = A[M,HID] @ Bt[N,HID]^T + bias.
// MODE 1: V proj A=Wv^T (M=768 d), B=x (N=T pos) -> vtb [s][h][d][pos].
// MODE 2: final proj fp32 = acc + bias + resid.
// ---------------------------------------------------------------------------
constexpr int SEGSZ = 528;   // elements per 8-row segment: 1024B data + 32B pad

template <int MODE>
__global__ __launch_bounds__(256)
void gemm_lds(const __bf16* __restrict__ A, const __bf16* __restrict__ Bt,
              const float* __restrict__ bias, __bf16* __restrict__ outb,
              const __bf16* __restrict__ resid, float* __restrict__ outf,
              float scale) {
    int tid = threadIdx.x, wave = tid >> 6, lane = tid & 63;
    int lr = lane & 15, quad = lane >> 4;
    int wm = wave >> 1, wn = wave & 1;
    long m0 = (long)blockIdx.x * 128;
    int  n0 = blockIdx.y * 128;

    __shared__ __align__(16) __bf16 As[16 * SEGSZ];
    __shared__ __align__(16) __bf16 Bs[16 * SEGSZ];

    const f32x4 vzero = {0.f, 0.f, 0.f, 0.f};
    f32x4 acc[4][4];
#pragma unroll
    for (int ms = 0; ms < 4; ms++)
#pragma unroll
        for (int ns = 0; ns < 4; ns++) acc[ms][ns] = vzero;

    const __bf16* ga = A  + (long)(m0 + wave * 32 + (lane >> 3)) * HID + (lane & 7) * 8;
    const __bf16* gb = Bt + (long)(n0 + wave * 32 + (lane >> 3)) * HID + (lane & 7) * 8;
    __bf16* la = As + wave * 4 * SEGSZ;
    __bf16* lb = Bs + wave * 4 * SEGSZ;

    int fbase = (lr >> 3) * SEGSZ + (lr & 7) * 64 + quad * 8;

    for (int k0 = 0; k0 < HID; k0 += 64) {
#pragma unroll
        for (int j = 0; j < 4; j++) {
            gld16(ga + (long)j * 8 * HID + k0, la + j * SEGSZ);
            gld16(gb + (long)j * 8 * HID + k0, lb + j * SEGSZ);
        }
        __syncthreads();
#pragma unroll
        for (int kk = 0; kk < 64; kk += 32) {
            bf16x8 af[4], bfr[4];
#pragma unroll
            for (int ms = 0; ms < 4; ms++)
                af[ms] = *(const bf16x8*)&As[fbase + (wm * 8 + ms * 2) * SEGSZ + kk];
#pragma unroll
            for (int ns = 0; ns < 4; ns++)
                bfr[ns] = *(const bf16x8*)&Bs[fbase + (wn * 8 + ns * 2) * SEGSZ + kk];
#pragma unroll
            for (int ms = 0; ms < 4; ms++)
#pragma unroll
                for (int ns = 0; ns < 4; ns++)
                    acc[ms][ns] = MFMA16(af[ms], bfr[ns], acc[ms][ns]);
        }
        __syncthreads();
    }

    if (MODE == 1) {
#pragma unroll
        for (int ms = 0; ms < 4; ms++)
#pragma unroll
        for (int r = 0; r < 4; r++) {
            int d = (int)(m0 + wm * 64 + ms * 16 + quad * 4 + r);   // 0..767
            float bv = bias[d];
            int hh = d >> 6, dd = d & 63;
#pragma unroll
            for (int ns = 0; ns < 4; ns++) {
                int posg = n0 + wn * 64 + ns * 16 + lr;
                int sq = posg >> 11, pos = posg & (SEQ - 1);
                outb[((long)((sq * NH + hh) * HD + dd) << 11) + pos] =
                    (__bf16)(acc[ms][ns][r] + bv);
            }
        }
    } else { // MODE 2
#pragma unroll
        for (int ns = 0; ns < 4; ns++) {
            int col = n0 + wn * 64 + ns * 16 + lr;
            float bv = bias[col];
#pragma unroll
            for (int ms = 0; ms < 4; ms++)
#pragma unroll
            for (int r = 0; r < 4; r++) {
                long row = m0 + wm * 64 + ms * 16 + quad * 4 + r;
                outf[row * HID + col] = acc[ms][ns][r] + bv + (float)resid[row * HID + col];
            }
        }
    }
}

// ---------------------------------------------------------------------------
// Fused Q+K projection: one staged A-tile feeds BOTH 128-wide Q and K tiles.
// ---------------------------------------------------------------------------
__global__ __launch_bounds__(256, 2)
void gemm_qk(const __bf16* __restrict__ A, const __bf16* __restrict__ Btq,
             const __bf16* __restrict__ Btk,
             const float* __restrict__ biasq, const float* __restrict__ biask,
             __bf16* __restrict__ outq, __bf16* __restrict__ outk) {
    int tid = threadIdx.x, wave = tid >> 6, lane = tid & 63;
    int lr = lane & 15, quad = lane >> 4;
    int wm = wave >> 1, wn = wave & 1;
    long m0 = (long)blockIdx.x * 128;
    int  n0 = blockIdx.y * 128;

    __shared__ __align__(16) __bf16 As[16 * SEGSZ];
    __shared__ __align__(16) __bf16 Bqs[16 * SEGSZ];
    __shared__ __align__(16) __bf16 Bks[16 * SEGSZ];

    const f32x4 vzero = {0.f, 0.f, 0.f, 0.f};
    f32x4 accq[4][4], acck[4][4];
#pragma unroll
    for (int ms = 0; ms < 4; ms++)
#pragma unroll
        for (int ns = 0; ns < 4; ns++) { accq[ms][ns] = vzero; acck[ms][ns] = vzero; }

    const __bf16* ga = A   + (long)(m0 + wave * 32 + (lane >> 3)) * HID + (lane & 7) * 8;
    const __bf16* gq = Btq + (long)(n0 + wave * 32 + (lane >> 3)) * HID + (lane & 7) * 8;
    const __bf16* gk = Btk + (long)(n0 + wave * 32 + (lane >> 3)) * HID + (lane & 7) * 8;
    __bf16* la = As  + wave * 4 * SEGSZ;
    __bf16* lq = Bqs + wave * 4 * SEGSZ;
    __bf16* lk = Bks + wave * 4 * SEGSZ;

    int fbase = (lr >> 3) * SEGSZ + (lr & 7) * 64 + quad * 8;

    for (int k0 = 0; k0 < HID; k0 += 64) {
#pragma unroll
        for (int j = 0; j < 4; j++) {
            gld16(ga + (long)j * 8 * HID + k0, la + j * SEGSZ);
            gld16(gq + (long)j * 8 * HID + k0, lq + j * SEGSZ);
            gld16(gk + (long)j * 8 * HID + k0, lk + j * SEGSZ);
        }
        __syncthreads();
#pragma unroll
        for (int kk = 0; kk < 64; kk += 32) {
            bf16x8 af[4], bqf[4], bkf[4];
#pragma unroll
            for (int ms = 0; ms < 4; ms++)
                af[ms] = *(const bf16x8*)&As[fbase + (wm * 8 + ms * 2) * SEGSZ + kk];
#pragma unroll
            for (int ns = 0; ns < 4; ns++) {
                bqf[ns] = *(const bf16x8*)&Bqs[fbase + (wn * 8 + ns * 2) * SEGSZ + kk];
                bkf[ns] = *(const bf16x8*)&Bks[fbase + (wn * 8 + ns * 2) * SEGSZ + kk];
            }
#pragma unroll
            for (int ms = 0; ms < 4; ms++)
#pragma unroll
                for (int ns = 0; ns < 4; ns++) {
                    accq[ms][ns] = MFMA16(af[ms], bqf[ns], accq[ms][ns]);
                    acck[ms][ns] = MFMA16(af[ms], bkf[ns], acck[ms][ns]);
                }
        }
        __syncthreads();
    }

    // epilogue: RoPE for Q (scale=QSCALE) then K (scale=1)
    int hb = n0 + wn * 64;
    float f1 = __builtin_amdgcn_exp2f(-(float)lr * L10K32);
    float f2 = __builtin_amdgcn_exp2f(-(float)(lr + 16) * L10K32);
    {
        float b0 = biasq[hb + lr],      b1 = biasq[hb + 16 + lr];
        float b2 = biasq[hb + 32 + lr], b3 = biasq[hb + 48 + lr];
#pragma unroll
        for (int ms = 0; ms < 4; ms++)
#pragma unroll
        for (int r = 0; r < 4; r++) {
            long row = m0 + wm * 64 + ms * 16 + quad * 4 + r;
            int pos = (int)(row & (SEQ - 1));
            float s1, c1, s2, c2;
            __sincosf((float)pos * f1, &s1, &c1);
            __sincosf((float)pos * f2, &s2, &c2);
            float v0 = accq[ms][0][r] + b0, v1 = accq[ms][1][r] + b1;
            float v2 = accq[ms][2][r] + b2, v3 = accq[ms][3][r] + b3;
            __bf16* ob = outq + row * HID + hb;
            ob[lr]      = (__bf16)((v0 * c1 - v2 * s1) * QSCALE);
            ob[16 + lr] = (__bf16)((v1 * c2 - v3 * s2) * QSCALE);
            ob[32 + lr] = (__bf16)((v2 * c1 + v0 * s1) * QSCALE);
            ob[48 + lr] = (__bf16)((v3 * c2 + v1 * s2) * QSCALE);
        }
    }
    {
        float b0 = biask[hb + lr],      b1 = biask[hb + 16 + lr];
        float b2 = biask[hb + 32 + lr], b3 = biask[hb + 48 + lr];
#pragma unroll
        for (int ms = 0; ms < 4; ms++)
#pragma unroll
        for (int r = 0; r < 4; r++) {
            long row = m0 + wm * 64 + ms * 16 + quad * 4 + r;
            int pos = (int)(row & (SEQ - 1));
            float s1, c1, s2, c2;
            __sincosf((float)pos * f1, &s1, &c1);
            __sincosf((float)pos * f2, &s2, &c2);
            float v0 = acck[ms][0][r] + b0, v1 = acck[ms][1][r] + b1;
            float v2 = acck[ms][2][r] + b2, v3 = acck[ms][3][r] + b3;
            __bf16* ob = outk + row * HID + hb;
            ob[lr]      = (__bf16)(v0 * c1 - v2 * s1);
            ob[16 + lr] = (__bf16)(v1 * c2 - v3 * s2);
            ob[32 + lr] = (__bf16)(v2 * c1 + v0 * s1);
            ob[48 + lr] = (__bf16)(v3 * c2 + v1 * s2);
        }
    }
}

// ---------------------------------------------------------------------------
// Flash attention v7: R6 pipeline + LDS-address diet + pinned residency.
//  * Flat 48KB LDS: K bufs at elem {0,4096,8192}, V bufs at {12288,+}.
//    4 per-lane base pointers precomputed once; ALL 16 ds_read_b128/body are
//    base[kk] + compile-time offset (buf=+4096el, row32=+2048el, V=+12288el;
//    max byte imm 44KB < 64KB) -> per-body address VALU ~0 (was ~16 XOR/shift
//    chains recomputed per read: compiler can't keep 48 addrs live).
//  * __launch_bounds__(512, 6): cap VGPR <=85 -> guarantees 3 blocks/CU
//    (6 waves/SIMD) co-resident; at 80 VGPR we sat exactly on the edge.
//  * Pipeline unchanged from R6: tri-buffer, 1 barrier/body, counted
//    vmcnt(2) (2 gld16/wave/tile), setprio around MFMA clusters, no-max
//    exp2-domain softmax, permlane32_swap P-redistribution, o in AGPRs.
//  * Grid NH*8*8=768; s=bb&7 pins sequence->XCD, qt fastest -> K/V L2-hot.
// ---------------------------------------------------------------------------
__global__ __launch_bounds__(512, 6)
void attn_kernel(const __bf16* __restrict__ q, const __bf16* __restrict__ k,
                 const __bf16* __restrict__ vt, __bf16* __restrict__ att) {
    int tid = threadIdx.x, wave = tid >> 6, lane = tid & 63;
    int c = lane & 31, hi = lane >> 5;
    int bb = blockIdx.x;
    int s  = bb & 7;           // sequence -> XCD
    int ii = bb >> 3;          // 0..95
    int h  = ii >> 3;          // head 0..11
    int qt = ii & 7;           // q-super-tile (256 rows), fastest within XCD
    long q0 = (long)s * SEQ + qt * 256 + wave * 32;

    // flat LDS: [0..3*4096) = K bufs 0..2, [12288..) = V bufs 0..2
    __shared__ __align__(16) __bf16 KV[6 * 4096];     // 48KB

    // Q fragments: qf[kk] = Q[q0+c][kk*16 + hi*8 .. +8]  (B-operand layout)
    bf16x8 qf[4];
    {
        const __bf16* qrow = q + (q0 + c) * HID + h * HD + hi * 8;
#pragma unroll
        for (int kk = 0; kk < 4; kk++)
            qf[kk] = *(const bf16x8*)(qrow + kk * 16);
    }

    f32x16 o[2] = {};
    float ls = 0.f;

    const __bf16* kg = k  + (long)s * SEQ * HID + h * HD;
    const __bf16* vg = vt + (long)(s * NH + h) * HD * SEQ;

    // staging lane constants; source chunk pre-swizzled by ^(row&7) so the
    // swizzled ds_reads see the right data (both-sides rule).
    int srow = lane >> 3;                 // row within 8-row group (0..7)
    int sgch = (lane & 7) ^ srow;         // swizzled source 16B-chunk

    // per-lane LDS read base pointers (loop-invariant; 4 VGPRs).
    // read of global chunk j=kk*2+hi of row R: LDS[R][j ^ (R&7)]; (R&7)==(c&7)
    // for both R=c and R=32+c.
    const __bf16* pb4[4];
#pragma unroll
    for (int kk = 0; kk < 4; kk++)
        pb4[kk] = KV + c * 64 + ((((kk << 1) + hi) ^ (c & 7)) << 3);

#define STAGE(bufi, kv)                                                         \
    {                                                                           \
        gld16(kg + (long)((kv) + wave * 8 + srow) * HID + sgch * 8,             \
              KV + (bufi) * 4096 + wave * 512);                                 \
        gld16(vg + (long)(wave * 8 + srow) * SEQ + (kv) + sgch * 8,             \
              KV + 12288 + (bufi) * 4096 + wave * 512);                         \
    }

#define ATTN_BODY(BUF)                                                          \
    {                                                                           \
        f32x16 st0 = {}, st1 = {};                                              \
        __builtin_amdgcn_s_setprio(1);                                          \
        _Pragma("unroll")                                                       \
        for (int kk = 0; kk < 4; kk++) {                                        \
            bf16x8 kf0 = *(const bf16x8*)(pb4[kk] + (BUF) * 4096);              \
            st0 = MFMA32(kf0, qf[kk], st0);                                     \
            bf16x8 kf1 = *(const bf16x8*)(pb4[kk] + (BUF) * 4096 + 2048);       \
            st1 = MFMA32(kf1, qf[kk], st1);                                     \
        }                                                                       \
        __builtin_amdgcn_s_setprio(0);                                          \
        bf16x8 pb[4];                                                           \
        _Pragma("unroll")                                                       \
        for (int kh = 0; kh < 2; kh++) {                                        \
            unsigned pk[8];                                                     \
            _Pragma("unroll")                                                   \
            for (int i = 0; i < 8; i++) {                                       \
                float e0 = __builtin_amdgcn_exp2f(kh ? st1[2 * i] : st0[2 * i]);        \
                float e1 = __builtin_amdgcn_exp2f(kh ? st1[2 * i + 1] : st0[2 * i + 1]);\
                ls += e0 + e1;                                                  \
                pk[i] = pkbf(e0, e1);                                           \
            }                                                                   \
            _Pragma("unroll")                                                   \
            for (int b = 0; b < 2; b++) {                                       \
                u32x2 r02 = __builtin_amdgcn_permlane32_swap(                   \
                    pk[4 * b + 0], pk[4 * b + 2], false, false);                \
                u32x2 r13 = __builtin_amdgcn_permlane32_swap(                   \
                    pk[4 * b + 1], pk[4 * b + 3], false, false);                \
                union { unsigned u[4]; bf16x8 v; } pu;                          \
                pu.u[0] = r02[0]; pu.u[1] = r13[0];                             \
                pu.u[2] = r02[1]; pu.u[3] = r13[1];                             \
                pb[2 * kh + b] = pu.v;                                          \
            }                                                                   \
        }                                                                       \
        __builtin_amdgcn_s_setprio(1);                                          \
        _Pragma("unroll")                                                       \
        for (int kk = 0; kk < 4; kk++) {                                        \
            bf16x8 vf0 = *(const bf16x8*)(pb4[kk] + 12288 + (BUF) * 4096);      \
            o[0] = MFMA32(vf0, pb[kk], o[0]);                                   \
            bf16x8 vf1 = *(const bf16x8*)(pb4[kk] + 12288 + (BUF) * 4096 + 2048); \
            o[1] = MFMA32(vf1, pb[kk], o[1]);                                   \
        }                                                                       \
        __builtin_amdgcn_s_setprio(0);                                          \
    }

#define WAITV(N) asm volatile("s_waitcnt vmcnt(" #N ")" ::: "memory")
#define BAR()    asm volatile("s_barrier" ::: "memory")

    STAGE(0, 0)
    STAGE(1, 64)              // 4 loads in flight per wave (tiles 0,1)

    // main loop: 30 bodies (tiles 0..29), staging tiles 2..31, unroll-3 for
    // compile-time buffer indices.  One barrier per body.
#pragma unroll 1
    for (int u = 0; u < 10; u++) {
        int kv = u * 3 * 64;
        WAITV(2); BAR();                 // tile 3u landed (all waves); body 3u-1 done
        STAGE(2, kv + 2 * 64)
        ATTN_BODY(0)
        WAITV(2); BAR();
        STAGE(0, kv + 3 * 64)
        ATTN_BODY(1)
        WAITV(2); BAR();
        STAGE(1, kv + 4 * 64)
        ATTN_BODY(2)
    }
    // tail: tiles 30 (buf0), 31 (buf1); nothing more to stage
    WAITV(2); BAR();
    ATTN_BODY(0)
    WAITV(0); BAR();
    ATTN_BODY(1)

#undef WAITV
#undef BAR
#undef STAGE
#undef ATTN_BODY

    // ---- epilogue: combine lane-half sums, normalize, pack, store ----
    ls += __shfl_xor(ls, 32);
    float inv = 1.0f / ls;
    __bf16* ob = att + (q0 + c) * HID + h * HD;
#pragma unroll
    for (int dh = 0; dh < 2; dh++)
#pragma unroll
        for (int a = 0; a < 4; a++) {
            unsigned lo  = pkbf(o[dh][4 * a] * inv,     o[dh][4 * a + 1] * inv);
            unsigned hi2 = pkbf(o[dh][4 * a + 2] * inv, o[dh][4 * a + 3] * inv);
            int d = dh * 32 + a * 8 + hi * 4;
            *(unsigned long long*)&ob[d] =
                ((unsigned long long)hi2 << 32) | lo;
        }
}

// ---------------------------------------------------------------------------
extern "C" void kernel_launch(void* const* d_in, const int* in_sizes, int n_in,
                              void* d_out, int out_size, void* d_ws, size_t ws_size,
                              hipStream_t stream) {
    const float* hs    = (const float*)d_in[0];
    const float* normw = (const float*)d_in[3];
    const float* normb = (const float*)d_in[4];
    const float* Wq = (const float*)d_in[5];
    const float* bq = (const float*)d_in[6];
    const float* Wk = (const float*)d_in[7];
    const float* bk = (const float*)d_in[8];
    const float* Wv = (const float*)d_in[9];
    const float* bv = (const float*)d_in[10];
    const float* Wo = (const float*)d_in[11];
    const float* bo = (const float*)d_in[12];

    __bf16* base = (__bf16*)d_ws;
    __bf16* x   = base;            // SZ
    __bf16* qb  = base + SZ;       // SZ
    __bf16* kb  = base + 2 * SZ;   // SZ
    __bf16* vtb = base + 3 * SZ;   // SZ  ([s][h][d][pos])
    __bf16* att = base + 4 * SZ;   // SZ
    __bf16* wqt = base + 5 * SZ;
    __bf16* wkt = wqt + WELE;
    __bf16* wvt = wkt + WELE;
    __bf16* wot = wvt + WELE;

    wconv_kernel<<<dim3(12, 12, 4), 256, 0, stream>>>(Wq, wqt, Wk, wkt, Wv, wvt, Wo, wot);

    ln_kernel<<<(int)T, 256, 0, stream>>>(hs, normw, normb, x);

    gemm_qk<<<dim3(T / 128, HID / 128), 256, 0, stream>>>(x, wqt, wkt, bq, bk, qb, kb);
    gemm_lds<1><<<dim3(HID / 128, T / 128), 256, 0, stream>>>(wvt, x, bv, vtb, nullptr, nullptr, 1.0f);

    attn_kernel<<<dim3(NH * 8 * 8), 512, 0, stream>>>(qb, kb, vtb, att);

    gemm_lds<2><<<dim3(T / 128, HID / 128), 256, 0, stream>>>(att, wot, bo, nullptr, x, (float*)d_out, 1.0f);
}

// Round 8
// 387.441 us; speedup vs baseline: 2.3608x; 2.3608x over previous
//
#include <hip/hip_runtime.h>

typedef __bf16 bf16x8 __attribute__((ext_vector_type(8)));
typedef float  f32x4  __attribute__((ext_vector_type(4)));
typedef float  f32x16 __attribute__((ext_vector_type(16)));
typedef unsigned u32x2 __attribute__((ext_vector_type(2)));

#define MFMA16(a,b,c) __builtin_amdgcn_mfma_f32_16x16x32_bf16((a),(b),(c),0,0,0)
#define MFMA32(a,b,c) __builtin_amdgcn_mfma_f32_32x32x16_bf16((a),(b),(c),0,0,0)

constexpr int  HID  = 768;
constexpr long T    = 16384;          // NUM_SEQS * SEQ_LEN
constexpr long SZ   = T * HID;        // 12,582,912 elements
constexpr int  SEQ  = 2048;
constexpr int  NH   = 12;
constexpr int  HD   = 64;
constexpr int  WELE = HID * HID;      // 589,824

// Q pre-scale: (1/sqrt(64)) * log2(e)  -> softmax done in exp2 domain
constexpr float QSCALE = 0.125f * 1.4426950408889634f;
// log2(10000)/32 for RoPE inv_freq = 2^(-d * L10K32)
constexpr float L10K32 = 13.287712379549449f / 32.0f;

__device__ __forceinline__ unsigned pkbf(float a, float b) {
    union { __bf16 h[2]; unsigned u; } x;
    x.h[0] = (__bf16)a; x.h[1] = (__bf16)b; return x.u;
}

// async global->LDS, 16B per lane; LDS dest = uniform base + lane*16
__device__ __forceinline__ void gld16(const __bf16* g, __bf16* l) {
    __builtin_amdgcn_global_load_lds(
        (const __attribute__((address_space(1))) unsigned int*)g,
        (__attribute__((address_space(3))) unsigned int*)l, 16, 0, 0);
}

// ---------------------------------------------------------------------------
// Weight convert+transpose, LDS-tiled. Wt[n][k] = bf16(W[k][n]).
// ---------------------------------------------------------------------------
__global__ __launch_bounds__(256)
void wconv_kernel(const float* __restrict__ W0, __bf16* __restrict__ T0,
                  const float* __restrict__ W1, __bf16* __restrict__ T1,
                  const float* __restrict__ W2, __bf16* __restrict__ T2,
                  const float* __restrict__ W3, __bf16* __restrict__ T3) {
    const float* W; __bf16* Wt;
    switch (blockIdx.z) {
        case 0: W = W0; Wt = T0; break;
        case 1: W = W1; Wt = T1; break;
        case 2: W = W2; Wt = T2; break;
        default: W = W3; Wt = T3; break;
    }
    __shared__ float tile[64][65];
    int n0 = blockIdx.x * 64, k0 = blockIdx.y * 64;
    int c = threadIdx.x & 63, rr = threadIdx.x >> 6;
#pragma unroll
    for (int i = 0; i < 16; i++) {
        int r = i * 4 + rr;
        tile[r][c] = W[(long)(k0 + r) * HID + n0 + c];
    }
    __syncthreads();
#pragma unroll
    for (int i = 0; i < 16; i++) {
        int r = i * 4 + rr;
        Wt[(long)(n0 + r) * HID + k0 + c] = (__bf16)tile[c][r];
    }
}

// ---------------------------------------------------------------------------
// LayerNorm
// ---------------------------------------------------------------------------
__global__ __launch_bounds__(256)
void ln_kernel(const float* __restrict__ hs, const float* __restrict__ w,
               const float* __restrict__ b, __bf16* __restrict__ xbf) {
    int row = blockIdx.x, tid = threadIdx.x;
    const float* hr = hs + (long)row * HID;
    float v0 = hr[tid], v1 = hr[tid + 256], v2 = hr[tid + 512];
    float s  = v0 + v1 + v2;
    float s2 = v0 * v0 + v1 * v1 + v2 * v2;
#pragma unroll
    for (int off = 1; off < 64; off <<= 1) {
        s  += __shfl_xor(s, off);
        s2 += __shfl_xor(s2, off);
    }
    __shared__ float red[8];
    int wave = tid >> 6;
    if ((tid & 63) == 0) { red[wave] = s; red[4 + wave] = s2; }
    __syncthreads();
    s  = red[0] + red[1] + red[2] + red[3];
    s2 = red[4] + red[5] + red[6] + red[7];
    float mu   = s * (1.0f / HID);
    float var  = s2 * (1.0f / HID) - mu * mu;
    float rstd = rsqrtf(var + 1e-12f);
    long base = (long)row * HID;
    xbf[base + tid]       = (__bf16)((v0 - mu) * rstd * w[tid]       + b[tid]);
    xbf[base + tid + 256] = (__bf16)((v1 - mu) * rstd * w[tid + 256] + b[tid + 256]);
    xbf[base + tid + 512] = (__bf16)((v2 - mu) * rstd * w[tid + 512] + b[tid + 512]);
}

// ---------------------------------------------------------------------------
// GEMM, m97-style: C[M,N] = A[M,HID] @ Bt[N,HID]^T + bias.
// MODE 1: V proj A=Wv^T (M=768 d), B=x (N=T pos) -> vtb [s][h][d][pos].
// MODE 2: final proj fp32 = acc + bias + resid.
// ---------------------------------------------------------------------------
constexpr int SEGSZ = 528;   // elements per 8-row segment: 1024B data + 32B pad

template <int MODE>
__global__ __launch_bounds__(256)
void gemm_lds(const __bf16* __restrict__ A, const __bf16* __restrict__ Bt,
              const float* __restrict__ bias, __bf16* __restrict__ outb,
              const __bf16* __restrict__ resid, float* __restrict__ outf,
              float scale) {
    int tid = threadIdx.x, wave = tid >> 6, lane = tid & 63;
    int lr = lane & 15, quad = lane >> 4;
    int wm = wave >> 1, wn = wave & 1;
    long m0 = (long)blockIdx.x * 128;
    int  n0 = blockIdx.y * 128;

    __shared__ __align__(16) __bf16 As[16 * SEGSZ];
    __shared__ __align__(16) __bf16 Bs[16 * SEGSZ];

    const f32x4 vzero = {0.f, 0.f, 0.f, 0.f};
    f32x4 acc[4][4];
#pragma unroll
    for (int ms = 0; ms < 4; ms++)
#pragma unroll
        for (int ns = 0; ns < 4; ns++) acc[ms][ns] = vzero;

    const __bf16* ga = A  + (long)(m0 + wave * 32 + (lane >> 3)) * HID + (lane & 7) * 8;
    const __bf16* gb = Bt + (long)(n0 + wave * 32 + (lane >> 3)) * HID + (lane & 7) * 8;
    __bf16* la = As + wave * 4 * SEGSZ;
    __bf16* lb = Bs + wave * 4 * SEGSZ;

    int fbase = (lr >> 3) * SEGSZ + (lr & 7) * 64 + quad * 8;

    for (int k0 = 0; k0 < HID; k0 += 64) {
#pragma unroll
        for (int j = 0; j < 4; j++) {
            gld16(ga + (long)j * 8 * HID + k0, la + j * SEGSZ);
            gld16(gb + (long)j * 8 * HID + k0, lb + j * SEGSZ);
        }
        __syncthreads();
#pragma unroll
        for (int kk = 0; kk < 64; kk += 32) {
            bf16x8 af[4], bfr[4];
#pragma unroll
            for (int ms = 0; ms < 4; ms++)
                af[ms] = *(const bf16x8*)&As[fbase + (wm * 8 + ms * 2) * SEGSZ + kk];
#pragma unroll
            for (int ns = 0; ns < 4; ns++)
                bfr[ns] = *(const bf16x8*)&Bs[fbase + (wn * 8 + ns * 2) * SEGSZ + kk];
#pragma unroll
            for (int ms = 0; ms < 4; ms++)
#pragma unroll
                for (int ns = 0; ns < 4; ns++)
                    acc[ms][ns] = MFMA16(af[ms], bfr[ns], acc[ms][ns]);
        }
        __syncthreads();
    }

    if (MODE == 1) {
#pragma unroll
        for (int ms = 0; ms < 4; ms++)
#pragma unroll
        for (int r = 0; r < 4; r++) {
            int d = (int)(m0 + wm * 64 + ms * 16 + quad * 4 + r);   // 0..767
            float bv = bias[d];
            int hh = d >> 6, dd = d & 63;
#pragma unroll
            for (int ns = 0; ns < 4; ns++) {
                int posg = n0 + wn * 64 + ns * 16 + lr;
                int sq = posg >> 11, pos = posg & (SEQ - 1);
                outb[((long)((sq * NH + hh) * HD + dd) << 11) + pos] =
                    (__bf16)(acc[ms][ns][r] + bv);
            }
        }
    } else { // MODE 2
#pragma unroll
        for (int ns = 0; ns < 4; ns++) {
            int col = n0 + wn * 64 + ns * 16 + lr;
            float bv = bias[col];
#pragma unroll
            for (int ms = 0; ms < 4; ms++)
#pragma unroll
            for (int r = 0; r < 4; r++) {
                long row = m0 + wm * 64 + ms * 16 + quad * 4 + r;
                outf[row * HID + col] = acc[ms][ns][r] + bv + (float)resid[row * HID + col];
            }
        }
    }
}

// ---------------------------------------------------------------------------
// Fused Q+K projection: one staged A-tile feeds BOTH 128-wide Q and K tiles.
// ---------------------------------------------------------------------------
__global__ __launch_bounds__(256, 2)
void gemm_qk(const __bf16* __restrict__ A, const __bf16* __restrict__ Btq,
             const __bf16* __restrict__ Btk,
             const float* __restrict__ biasq, const float* __restrict__ biask,
             __bf16* __restrict__ outq, __bf16* __restrict__ outk) {
    int tid = threadIdx.x, wave = tid >> 6, lane = tid & 63;
    int lr = lane & 15, quad = lane >> 4;
    int wm = wave >> 1, wn = wave & 1;
    long m0 = (long)blockIdx.x * 128;
    int  n0 = blockIdx.y * 128;

    __shared__ __align__(16) __bf16 As[16 * SEGSZ];
    __shared__ __align__(16) __bf16 Bqs[16 * SEGSZ];
    __shared__ __align__(16) __bf16 Bks[16 * SEGSZ];

    const f32x4 vzero = {0.f, 0.f, 0.f, 0.f};
    f32x4 accq[4][4], acck[4][4];
#pragma unroll
    for (int ms = 0; ms < 4; ms++)
#pragma unroll
        for (int ns = 0; ns < 4; ns++) { accq[ms][ns] = vzero; acck[ms][ns] = vzero; }

    const __bf16* ga = A   + (long)(m0 + wave * 32 + (lane >> 3)) * HID + (lane & 7) * 8;
    const __bf16* gq = Btq + (long)(n0 + wave * 32 + (lane >> 3)) * HID + (lane & 7) * 8;
    const __bf16* gk = Btk + (long)(n0 + wave * 32 + (lane >> 3)) * HID + (lane & 7) * 8;
    __bf16* la = As  + wave * 4 * SEGSZ;
    __bf16* lq = Bqs + wave * 4 * SEGSZ;
    __bf16* lk = Bks + wave * 4 * SEGSZ;

    int fbase = (lr >> 3) * SEGSZ + (lr & 7) * 64 + quad * 8;

    for (int k0 = 0; k0 < HID; k0 += 64) {
#pragma unroll
        for (int j = 0; j < 4; j++) {
            gld16(ga + (long)j * 8 * HID + k0, la + j * SEGSZ);
            gld16(gq + (long)j * 8 * HID + k0, lq + j * SEGSZ);
            gld16(gk + (long)j * 8 * HID + k0, lk + j * SEGSZ);
        }
        __syncthreads();
#pragma unroll
        for (int kk = 0; kk < 64; kk += 32) {
            bf16x8 af[4], bqf[4], bkf[4];
#pragma unroll
            for (int ms = 0; ms < 4; ms++)
                af[ms] = *(const bf16x8*)&As[fbase + (wm * 8 + ms * 2) * SEGSZ + kk];
#pragma unroll
            for (int ns = 0; ns < 4; ns++) {
                bqf[ns] = *(const bf16x8*)&Bqs[fbase + (wn * 8 + ns * 2) * SEGSZ + kk];
                bkf[ns] = *(const bf16x8*)&Bks[fbase + (wn * 8 + ns * 2) * SEGSZ + kk];
            }
#pragma unroll
            for (int ms = 0; ms < 4; ms++)
#pragma unroll
                for (int ns = 0; ns < 4; ns++) {
                    accq[ms][ns] = MFMA16(af[ms], bqf[ns], accq[ms][ns]);
                    acck[ms][ns] = MFMA16(af[ms], bkf[ns], acck[ms][ns]);
                }
        }
        __syncthreads();
    }

    // epilogue: RoPE for Q (scale=QSCALE) then K (scale=1)
    int hb = n0 + wn * 64;
    float f1 = __builtin_amdgcn_exp2f(-(float)lr * L10K32);
    float f2 = __builtin_amdgcn_exp2f(-(float)(lr + 16) * L10K32);
    {
        float b0 = biasq[hb + lr],      b1 = biasq[hb + 16 + lr];
        float b2 = biasq[hb + 32 + lr], b3 = biasq[hb + 48 + lr];
#pragma unroll
        for (int ms = 0; ms < 4; ms++)
#pragma unroll
        for (int r = 0; r < 4; r++) {
            long row = m0 + wm * 64 + ms * 16 + quad * 4 + r;
            int pos = (int)(row & (SEQ - 1));
            float s1, c1, s2, c2;
            __sincosf((float)pos * f1, &s1, &c1);
            __sincosf((float)pos * f2, &s2, &c2);
            float v0 = accq[ms][0][r] + b0, v1 = accq[ms][1][r] + b1;
            float v2 = accq[ms][2][r] + b2, v3 = accq[ms][3][r] + b3;
            __bf16* ob = outq + row * HID + hb;
            ob[lr]      = (__bf16)((v0 * c1 - v2 * s1) * QSCALE);
            ob[16 + lr] = (__bf16)((v1 * c2 - v3 * s2) * QSCALE);
            ob[32 + lr] = (__bf16)((v2 * c1 + v0 * s1) * QSCALE);
            ob[48 + lr] = (__bf16)((v3 * c2 + v1 * s2) * QSCALE);
        }
    }
    {
        float b0 = biask[hb + lr],      b1 = biask[hb + 16 + lr];
        float b2 = biask[hb + 32 + lr], b3 = biask[hb + 48 + lr];
#pragma unroll
        for (int ms = 0; ms < 4; ms++)
#pragma unroll
        for (int r = 0; r < 4; r++) {
            long row = m0 + wm * 64 + ms * 16 + quad * 4 + r;
            int pos = (int)(row & (SEQ - 1));
            float s1, c1, s2, c2;
            __sincosf((float)pos * f1, &s1, &c1);
            __sincosf((float)pos * f2, &s2, &c2);
            float v0 = acck[ms][0][r] + b0, v1 = acck[ms][1][r] + b1;
            float v2 = acck[ms][2][r] + b2, v3 = acck[ms][3][r] + b3;
            __bf16* ob = outk + row * HID + hb;
            ob[lr]      = (__bf16)(v0 * c1 - v2 * s1);
            ob[16 + lr] = (__bf16)(v1 * c2 - v3 * s2);
            ob[32 + lr] = (__bf16)(v2 * c1 + v0 * s1);
            ob[48 + lr] = (__bf16)(v3 * c2 + v1 * s2);
        }
    }
}

// ---------------------------------------------------------------------------
// Flash attention v8 = v7 minus the min-waves launch bound (R7 post-mortem:
// __launch_bounds__(512,6) forced 40 VGPR -> accumulator spill to scratch,
// FETCH 37MB->1.27GB, 154->686us.  gfx950 unified VGPR/AGPR: never pin
// min-waves on an MFMA-accumulator kernel near the allocation boundary).
//  * Flat 48KB LDS, per-lane base pointers, all ds_reads base+imm offset.
//  * Tri-buffer, 1 barrier/body, counted vmcnt(2), setprio, no-max exp2
//    softmax, permlane32_swap P redistribution, o in AGPRs.
//  * Grid NH*8*8=768; s=bb&7 pins sequence->XCD, qt fastest -> K/V L2-hot.
// ---------------------------------------------------------------------------
__global__ __launch_bounds__(512)
void attn_kernel(const __bf16* __restrict__ q, const __bf16* __restrict__ k,
                 const __bf16* __restrict__ vt, __bf16* __restrict__ att) {
    int tid = threadIdx.x, wave = tid >> 6, lane = tid & 63;
    int c = lane & 31, hi = lane >> 5;
    int bb = blockIdx.x;
    int s  = bb & 7;           // sequence -> XCD
    int ii = bb >> 3;          // 0..95
    int h  = ii >> 3;          // head 0..11
    int qt = ii & 7;           // q-super-tile (256 rows), fastest within XCD
    long q0 = (long)s * SEQ + qt * 256 + wave * 32;

    // flat LDS: [0..3*4096) = K bufs 0..2, [12288..) = V bufs 0..2
    __shared__ __align__(16) __bf16 KV[6 * 4096];     // 48KB

    // Q fragments: qf[kk] = Q[q0+c][kk*16 + hi*8 .. +8]  (B-operand layout)
    bf16x8 qf[4];
    {
        const __bf16* qrow = q + (q0 + c) * HID + h * HD + hi * 8;
#pragma unroll
        for (int kk = 0; kk < 4; kk++)
            qf[kk] = *(const bf16x8*)(qrow + kk * 16);
    }

    f32x16 o[2] = {};
    float ls = 0.f;

    const __bf16* kg = k  + (long)s * SEQ * HID + h * HD;
    const __bf16* vg = vt + (long)(s * NH + h) * HD * SEQ;

    // staging lane constants; source chunk pre-swizzled by ^(row&7) so the
    // swizzled ds_reads see the right data (both-sides rule).
    int srow = lane >> 3;                 // row within 8-row group (0..7)
    int sgch = (lane & 7) ^ srow;         // swizzled source 16B-chunk

    // per-lane LDS read base pointers (loop-invariant; 4 VGPRs).
    const __bf16* pb4[4];
#pragma unroll
    for (int kk = 0; kk < 4; kk++)
        pb4[kk] = KV + c * 64 + ((((kk << 1) + hi) ^ (c & 7)) << 3);

#define STAGE(bufi, kv)                                                         \
    {                                                                           \
        gld16(kg + (long)((kv) + wave * 8 + srow) * HID + sgch * 8,             \
              KV + (bufi) * 4096 + wave * 512);                                 \
        gld16(vg + (long)(wave * 8 + srow) * SEQ + (kv) + sgch * 8,             \
              KV + 12288 + (bufi) * 4096 + wave * 512);                         \
    }

#define ATTN_BODY(BUF)                                                          \
    {                                                                           \
        f32x16 st0 = {}, st1 = {};                                              \
        __builtin_amdgcn_s_setprio(1);                                          \
        _Pragma("unroll")                                                       \
        for (int kk = 0; kk < 4; kk++) {                                        \
            bf16x8 kf0 = *(const bf16x8*)(pb4[kk] + (BUF) * 4096);              \
            st0 = MFMA32(kf0, qf[kk], st0);                                     \
            bf16x8 kf1 = *(const bf16x8*)(pb4[kk] + (BUF) * 4096 + 2048);       \
            st1 = MFMA32(kf1, qf[kk], st1);                                     \
        }                                                                       \
        __builtin_amdgcn_s_setprio(0);                                          \
        bf16x8 pb[4];                                                           \
        _Pragma("unroll")                                                       \
        for (int kh = 0; kh < 2; kh++) {                                        \
            unsigned pk[8];                                                     \
            _Pragma("unroll")                                                   \
            for (int i = 0; i < 8; i++) {                                       \
                float e0 = __builtin_amdgcn_exp2f(kh ? st1[2 * i] : st0[2 * i]);        \
                float e1 = __builtin_amdgcn_exp2f(kh ? st1[2 * i + 1] : st0[2 * i + 1]);\
                ls += e0 + e1;                                                  \
                pk[i] = pkbf(e0, e1);                                           \
            }                                                                   \
            _Pragma("unroll")                                                   \
            for (int b = 0; b < 2; b++) {                                       \
                u32x2 r02 = __builtin_amdgcn_permlane32_swap(                   \
                    pk[4 * b + 0], pk[4 * b + 2], false, false);                \
                u32x2 r13 = __builtin_amdgcn_permlane32_swap(                   \
                    pk[4 * b + 1], pk[4 * b + 3], false, false);                \
                union { unsigned u[4]; bf16x8 v; } pu;                          \
                pu.u[0] = r02[0]; pu.u[1] = r13[0];                             \
                pu.u[2] = r02[1]; pu.u[3] = r13[1];                             \
                pb[2 * kh + b] = pu.v;                                          \
            }                                                                   \
        }                                                                       \
        __builtin_amdgcn_s_setprio(1);                                          \
        _Pragma("unroll")                                                       \
        for (int kk = 0; kk < 4; kk++) {                                        \
            bf16x8 vf0 = *(const bf16x8*)(pb4[kk] + 12288 + (BUF) * 4096);      \
            o[0] = MFMA32(vf0, pb[kk], o[0]);                                   \
            bf16x8 vf1 = *(const bf16x8*)(pb4[kk] + 12288 + (BUF) * 4096 + 2048); \
            o[1] = MFMA32(vf1, pb[kk], o[1]);                                   \
        }                                                                       \
        __builtin_amdgcn_s_setprio(0);                                          \
    }

#define WAITV(N) asm volatile("s_waitcnt vmcnt(" #N ")" ::: "memory")
#define BAR()    asm volatile("s_barrier" ::: "memory")

    STAGE(0, 0)
    STAGE(1, 64)              // 4 loads in flight per wave (tiles 0,1)

    // main loop: 30 bodies (tiles 0..29), staging tiles 2..31, unroll-3 for
    // compile-time buffer indices.  One barrier per body.
#pragma unroll 1
    for (int u = 0; u < 10; u++) {
        int kv = u * 3 * 64;
        WAITV(2); BAR();                 // tile 3u landed (all waves); body 3u-1 done
        STAGE(2, kv + 2 * 64)
        ATTN_BODY(0)
        WAITV(2); BAR();
        STAGE(0, kv + 3 * 64)
        ATTN_BODY(1)
        WAITV(2); BAR();
        STAGE(1, kv + 4 * 64)
        ATTN_BODY(2)
    }
    // tail: tiles 30 (buf0), 31 (buf1); nothing more to stage
    WAITV(2); BAR();
    ATTN_BODY(0)
    WAITV(0); BAR();
    ATTN_BODY(1)

#undef WAITV
#undef BAR
#undef STAGE
#undef ATTN_BODY

    // ---- epilogue: combine lane-half sums, normalize, pack, store ----
    ls += __shfl_xor(ls, 32);
    float inv = 1.0f / ls;
    __bf16* ob = att + (q0 + c) * HID + h * HD;
#pragma unroll
    for (int dh = 0; dh < 2; dh++)
#pragma unroll
        for (int a = 0; a < 4; a++) {
            unsigned lo  = pkbf(o[dh][4 * a] * inv,     o[dh][4 * a + 1] * inv);
            unsigned hi2 = pkbf(o[dh][4 * a + 2] * inv, o[dh][4 * a + 3] * inv);
            int d = dh * 32 + a * 8 + hi * 4;
            *(unsigned long long*)&ob[d] =
                ((unsigned long long)hi2 << 32) | lo;
        }
}

// ---------------------------------------------------------------------------
extern "C" void kernel_launch(void* const* d_in, const int* in_sizes, int n_in,
                              void* d_out, int out_size, void* d_ws, size_t ws_size,
                              hipStream_t stream) {
    const float* hs    = (const float*)d_in[0];
    const float* normw = (const float*)d_in[3];
    const float* normb = (const float*)d_in[4];
    const float* Wq = (const float*)d_in[5];
    const float* bq = (const float*)d_in[6];
    const float* Wk = (const float*)d_in[7];
    const float* bk = (const float*)d_in[8];
    const float* Wv = (const float*)d_in[9];
    const float* bv = (const float*)d_in[10];
    const float* Wo = (const float*)d_in[11];
    const float* bo = (const float*)d_in[12];

    __bf16* base = (__bf16*)d_ws;
    __bf16* x   = base;            // SZ
    __bf16* qb  = base + SZ;       // SZ
    __bf16* kb  = base + 2 * SZ;   // SZ
    __bf16* vtb = base + 3 * SZ;   // SZ  ([s][h][d][pos])
    __bf16* att = base + 4 * SZ;   // SZ
    __bf16* wqt = base + 5 * SZ;
    __bf16* wkt = wqt + WELE;
    __bf16* wvt = wkt + WELE;
    __bf16* wot = wvt + WELE;

    wconv_kernel<<<dim3(12, 12, 4), 256, 0, stream>>>(Wq, wqt, Wk, wkt, Wv, wvt, Wo, wot);

    ln_kernel<<<(int)T, 256, 0, stream>>>(hs, normw, normb, x);

    gemm_qk<<<dim3(T / 128, HID / 128), 256, 0, stream>>>(x, wqt, wkt, bq, bk, qb, kb);
    gemm_lds<1><<<dim3(HID / 128, T / 128), 256, 0, stream>>>(wvt, x, bv, vtb, nullptr, nullptr, 1.0f);

    attn_kernel<<<dim3(NH * 8 * 8), 512, 0, stream>>>(qb, kb, vtb, att);

    gemm_lds<2><<<dim3(T / 128, HID / 128), 256, 0, stream>>>(att, wot, bo, nullptr, x, (float*)d_out, 1.0f);
}

// Round 9
// 380.729 us; speedup vs baseline: 2.4024x; 1.0176x over previous
//
#include <hip/hip_runtime.h>

typedef __bf16 bf16x8 __attribute__((ext_vector_type(8)));
typedef float  f32x4  __attribute__((ext_vector_type(4)));
typedef float  f32x16 __attribute__((ext_vector_type(16)));
typedef unsigned u32x2 __attribute__((ext_vector_type(2)));

#define MFMA16(a,b,c) __builtin_amdgcn_mfma_f32_16x16x32_bf16((a),(b),(c),0,0,0)
#define MFMA32(a,b,c) __builtin_amdgcn_mfma_f32_32x32x16_bf16((a),(b),(c),0,0,0)

constexpr int  HID  = 768;
constexpr long T    = 16384;          // NUM_SEQS * SEQ_LEN
constexpr long SZ   = T * HID;        // 12,582,912 elements
constexpr int  SEQ  = 2048;
constexpr int  NH   = 12;
constexpr int  HD   = 64;
constexpr int  WELE = HID * HID;      // 589,824

// Q pre-scale: (1/sqrt(64)) * log2(e)  -> softmax done in exp2 domain
constexpr float QSCALE = 0.125f * 1.4426950408889634f;
// log2(10000)/32 for RoPE inv_freq = 2^(-d * L10K32)
constexpr float L10K32 = 13.287712379549449f / 32.0f;

__device__ __forceinline__ unsigned pkbf(float a, float b) {
    union { __bf16 h[2]; unsigned u; } x;
    x.h[0] = (__bf16)a; x.h[1] = (__bf16)b; return x.u;
}

// async global->LDS, 16B per lane; LDS dest = uniform base + lane*16
__device__ __forceinline__ void gld16(const __bf16* g, __bf16* l) {
    __builtin_amdgcn_global_load_lds(
        (const __attribute__((address_space(1))) unsigned int*)g,
        (__attribute__((address_space(3))) unsigned int*)l, 16, 0, 0);
}

#define WAITVN(N) asm volatile("s_waitcnt vmcnt(" #N ")" ::: "memory")
#define BARR()    asm volatile("s_barrier" ::: "memory")

// ---------------------------------------------------------------------------
// Weight convert+transpose, LDS-tiled. Wt[n][k] = bf16(W[k][n]).
// ---------------------------------------------------------------------------
__global__ __launch_bounds__(256)
void wconv_kernel(const float* __restrict__ W0, __bf16* __restrict__ T0,
                  const float* __restrict__ W1, __bf16* __restrict__ T1,
                  const float* __restrict__ W2, __bf16* __restrict__ T2,
                  const float* __restrict__ W3, __bf16* __restrict__ T3) {
    const float* W; __bf16* Wt;
    switch (blockIdx.z) {
        case 0: W = W0; Wt = T0; break;
        case 1: W = W1; Wt = T1; break;
        case 2: W = W2; Wt = T2; break;
        default: W = W3; Wt = T3; break;
    }
    __shared__ float tile[64][65];
    int n0 = blockIdx.x * 64, k0 = blockIdx.y * 64;
    int c = threadIdx.x & 63, rr = threadIdx.x >> 6;
#pragma unroll
    for (int i = 0; i < 16; i++) {
        int r = i * 4 + rr;
        tile[r][c] = W[(long)(k0 + r) * HID + n0 + c];
    }
    __syncthreads();
#pragma unroll
    for (int i = 0; i < 16; i++) {
        int r = i * 4 + rr;
        Wt[(long)(n0 + r) * HID + k0 + c] = (__bf16)tile[c][r];
    }
}

// ---------------------------------------------------------------------------
// LayerNorm
// ---------------------------------------------------------------------------
__global__ __launch_bounds__(256)
void ln_kernel(const float* __restrict__ hs, const float* __restrict__ w,
               const float* __restrict__ b, __bf16* __restrict__ xbf) {
    int row = blockIdx.x, tid = threadIdx.x;
    const float* hr = hs + (long)row * HID;
    float v0 = hr[tid], v1 = hr[tid + 256], v2 = hr[tid + 512];
    float s  = v0 + v1 + v2;
    float s2 = v0 * v0 + v1 * v1 + v2 * v2;
#pragma unroll
    for (int off = 1; off < 64; off <<= 1) {
        s  += __shfl_xor(s, off);
        s2 += __shfl_xor(s2, off);
    }
    __shared__ float red[8];
    int wave = tid >> 6;
    if ((tid & 63) == 0) { red[wave] = s; red[4 + wave] = s2; }
    __syncthreads();
    s  = red[0] + red[1] + red[2] + red[3];
    s2 = red[4] + red[5] + red[6] + red[7];
    float mu   = s * (1.0f / HID);
    float var  = s2 * (1.0f / HID) - mu * mu;
    float rstd = rsqrtf(var + 1e-12f);
    long base = (long)row * HID;
    xbf[base + tid]       = (__bf16)((v0 - mu) * rstd * w[tid]       + b[tid]);
    xbf[base + tid + 256] = (__bf16)((v1 - mu) * rstd * w[tid + 256] + b[tid + 256]);
    xbf[base + tid + 512] = (__bf16)((v2 - mu) * rstd * w[tid + 512] + b[tid + 512]);
}

// ---------------------------------------------------------------------------
// GEMM v2: 2-phase double-buffered pipeline (T3 minimum recipe).
// C[M,N] = A[M,HID] @ Bt[N,HID]^T + bias.  128x128 tile, 4 waves.
// Per K-step: {stage tile t+1 -> vmcnt(8) (tile t's 8 loads oldest) ->
// barrier -> MFMA on tile t -> barrier}.  Load flight hides under compute.
// MODE 1: V proj A=Wv^T (M=768 d), B=x (N=T pos) -> vtb [s][h][d][pos].
// MODE 2: final proj fp32 = acc + bias + resid.
// ---------------------------------------------------------------------------
constexpr int SEGSZ = 528;   // elements per 8-row segment: 1024B data + 32B pad
constexpr int BUFSZ = 16 * SEGSZ;

template <int MODE>
__global__ __launch_bounds__(256)
void gemm_lds(const __bf16* __restrict__ A, const __bf16* __restrict__ Bt,
              const float* __restrict__ bias, __bf16* __restrict__ outb,
              const __bf16* __restrict__ resid, float* __restrict__ outf,
              float scale) {
    int tid = threadIdx.x, wave = tid >> 6, lane = tid & 63;
    int lr = lane & 15, quad = lane >> 4;
    int wm = wave >> 1, wn = wave & 1;
    long m0 = (long)blockIdx.x * 128;
    int  n0 = blockIdx.y * 128;

    __shared__ __align__(16) __bf16 As[2][BUFSZ];
    __shared__ __align__(16) __bf16 Bs[2][BUFSZ];

    const f32x4 vzero = {0.f, 0.f, 0.f, 0.f};
    f32x4 acc[4][4];
#pragma unroll
    for (int ms = 0; ms < 4; ms++)
#pragma unroll
        for (int ns = 0; ns < 4; ns++) acc[ms][ns] = vzero;

    const __bf16* ga = A  + (long)(m0 + wave * 32 + (lane >> 3)) * HID + (lane & 7) * 8;
    const __bf16* gb = Bt + (long)(n0 + wave * 32 + (lane >> 3)) * HID + (lane & 7) * 8;

    int fbase = (lr >> 3) * SEGSZ + (lr & 7) * 64 + quad * 8;

#define GSTAGE(b, k0)                                                           \
    {                                                                           \
        _Pragma("unroll")                                                       \
        for (int j = 0; j < 4; j++) {                                           \
            gld16(ga + (long)j * 8 * HID + (k0), As[b] + wave * 4 * SEGSZ + j * SEGSZ); \
            gld16(gb + (long)j * 8 * HID + (k0), Bs[b] + wave * 4 * SEGSZ + j * SEGSZ); \
        }                                                                       \
    }

#define GCOMP(b)                                                                \
    {                                                                           \
        _Pragma("unroll")                                                       \
        for (int kk = 0; kk < 64; kk += 32) {                                   \
            bf16x8 af[4], bfr[4];                                               \
            _Pragma("unroll")                                                   \
            for (int ms = 0; ms < 4; ms++)                                      \
                af[ms] = *(const bf16x8*)&As[b][fbase + (wm * 8 + ms * 2) * SEGSZ + kk]; \
            _Pragma("unroll")                                                   \
            for (int ns = 0; ns < 4; ns++)                                      \
                bfr[ns] = *(const bf16x8*)&Bs[b][fbase + (wn * 8 + ns * 2) * SEGSZ + kk]; \
            _Pragma("unroll")                                                   \
            for (int ms = 0; ms < 4; ms++)                                      \
                _Pragma("unroll")                                               \
                for (int ns = 0; ns < 4; ns++)                                  \
                    acc[ms][ns] = MFMA16(af[ms], bfr[ns], acc[ms][ns]);         \
        }                                                                       \
    }

    GSTAGE(0, 0)
    // tiles 0..11 (HID/64 = 12); pair-unrolled for compile-time buffers
#pragma unroll 1
    for (int u = 0; u < 5; u++) {
        int k0 = u * 128;
        GSTAGE(1, k0 + 64)  WAITVN(8); BARR(); GCOMP(0) BARR();
        GSTAGE(0, k0 + 128) WAITVN(8); BARR(); GCOMP(1) BARR();
    }
    GSTAGE(1, 11 * 64) WAITVN(8); BARR(); GCOMP(0) BARR();
    WAITVN(0); BARR(); GCOMP(1)

#undef GSTAGE
#undef GCOMP

    if (MODE == 1) {
#pragma unroll
        for (int ms = 0; ms < 4; ms++)
#pragma unroll
        for (int r = 0; r < 4; r++) {
            int d = (int)(m0 + wm * 64 + ms * 16 + quad * 4 + r);   // 0..767
            float bv = bias[d];
            int hh = d >> 6, dd = d & 63;
#pragma unroll
            for (int ns = 0; ns < 4; ns++) {
                int posg = n0 + wn * 64 + ns * 16 + lr;
                int sq = posg >> 11, pos = posg & (SEQ - 1);
                outb[((long)((sq * NH + hh) * HD + dd) << 11) + pos] =
                    (__bf16)(acc[ms][ns][r] + bv);
            }
        }
    } else { // MODE 2
#pragma unroll
        for (int ns = 0; ns < 4; ns++) {
            int col = n0 + wn * 64 + ns * 16 + lr;
            float bv = bias[col];
#pragma unroll
            for (int ms = 0; ms < 4; ms++)
#pragma unroll
            for (int r = 0; r < 4; r++) {
                long row = m0 + wm * 64 + ms * 16 + quad * 4 + r;
                outf[row * HID + col] = acc[ms][ns][r] + bv + (float)resid[row * HID + col];
            }
        }
    }
}

// ---------------------------------------------------------------------------
// Fused Q+K projection, 2-phase: A (x, streamed) double-buffered with 2-tile
// prefetch depth; Bq/Bk (weights, L2-hot) single-buffered and staged right
// after the post-compute barrier (only ~L2 latency exposed per step).
// Per step t: COMPUTE(t) -> BAR -> STAGE_B(t+1), STAGE_A(t+2) -> vmcnt(4)
// (A(t+2) newest stays in flight; A(t+1)+B(t+1) drained) -> BAR.
// ---------------------------------------------------------------------------
__global__ __launch_bounds__(256, 2)
void gemm_qk(const __bf16* __restrict__ A, const __bf16* __restrict__ Btq,
             const __bf16* __restrict__ Btk,
             const float* __restrict__ biasq, const float* __restrict__ biask,
             __bf16* __restrict__ outq, __bf16* __restrict__ outk) {
    int tid = threadIdx.x, wave = tid >> 6, lane = tid & 63;
    int lr = lane & 15, quad = lane >> 4;
    int wm = wave >> 1, wn = wave & 1;
    long m0 = (long)blockIdx.x * 128;
    int  n0 = blockIdx.y * 128;

    __shared__ __align__(16) __bf16 As[2][BUFSZ];
    __shared__ __align__(16) __bf16 Bqs[BUFSZ];
    __shared__ __align__(16) __bf16 Bks[BUFSZ];

    const f32x4 vzero = {0.f, 0.f, 0.f, 0.f};
    f32x4 accq[4][4], acck[4][4];
#pragma unroll
    for (int ms = 0; ms < 4; ms++)
#pragma unroll
        for (int ns = 0; ns < 4; ns++) { accq[ms][ns] = vzero; acck[ms][ns] = vzero; }

    const __bf16* ga = A   + (long)(m0 + wave * 32 + (lane >> 3)) * HID + (lane & 7) * 8;
    const __bf16* gq = Btq + (long)(n0 + wave * 32 + (lane >> 3)) * HID + (lane & 7) * 8;
    const __bf16* gk = Btk + (long)(n0 + wave * 32 + (lane >> 3)) * HID + (lane & 7) * 8;

    int fbase = (lr >> 3) * SEGSZ + (lr & 7) * 64 + quad * 8;

#define QSTAGE_A(b, k0)                                                         \
    {                                                                           \
        _Pragma("unroll")                                                       \
        for (int j = 0; j < 4; j++)                                             \
            gld16(ga + (long)j * 8 * HID + (k0), As[b] + wave * 4 * SEGSZ + j * SEGSZ); \
    }
#define QSTAGE_B(k0)                                                            \
    {                                                                           \
        _Pragma("unroll")                                                       \
        for (int j = 0; j < 4; j++) {                                           \
            gld16(gq + (long)j * 8 * HID + (k0), Bqs + wave * 4 * SEGSZ + j * SEGSZ); \
            gld16(gk + (long)j * 8 * HID + (k0), Bks + wave * 4 * SEGSZ + j * SEGSZ); \
        }                                                                       \
    }
#define QCOMP(b)                                                                \
    {                                                                           \
        _Pragma("unroll")                                                       \
        for (int kk = 0; kk < 64; kk += 32) {                                   \
            bf16x8 af[4], bqf[4], bkf[4];                                       \
            _Pragma("unroll")                                                   \
            for (int ms = 0; ms < 4; ms++)                                      \
                af[ms] = *(const bf16x8*)&As[b][fbase + (wm * 8 + ms * 2) * SEGSZ + kk]; \
            _Pragma("unroll")                                                   \
            for (int ns = 0; ns < 4; ns++) {                                    \
                bqf[ns] = *(const bf16x8*)&Bqs[fbase + (wn * 8 + ns * 2) * SEGSZ + kk]; \
                bkf[ns] = *(const bf16x8*)&Bks[fbase + (wn * 8 + ns * 2) * SEGSZ + kk]; \
            }                                                                   \
            _Pragma("unroll")                                                   \
            for (int ms = 0; ms < 4; ms++)                                      \
                _Pragma("unroll")                                               \
                for (int ns = 0; ns < 4; ns++) {                                \
                    accq[ms][ns] = MFMA16(af[ms], bqf[ns], accq[ms][ns]);       \
                    acck[ms][ns] = MFMA16(af[ms], bkf[ns], acck[ms][ns]);       \
                }                                                               \
        }                                                                       \
    }

    QSTAGE_A(0, 0) QSTAGE_B(0) QSTAGE_A(1, 64)
    WAITVN(4); BARR();          // A0,B0 landed; A1 in flight

    // tiles 0..11; pair-unrolled
#pragma unroll 1
    for (int u = 0; u < 5; u++) {
        int k0 = u * 128;
        QCOMP(0) BARR();
        QSTAGE_B(k0 + 64)  QSTAGE_A(0, k0 + 128) WAITVN(4); BARR();
        QCOMP(1) BARR();
        QSTAGE_B(k0 + 128) QSTAGE_A(1, k0 + 192) WAITVN(4); BARR();
    }
    QCOMP(0) BARR();
    QSTAGE_B(11 * 64) WAITVN(0); BARR();
    QCOMP(1)

#undef QSTAGE_A
#undef QSTAGE_B
#undef QCOMP

    // epilogue: RoPE for Q (scale=QSCALE) then K (scale=1)
    int hb = n0 + wn * 64;
    float f1 = __builtin_amdgcn_exp2f(-(float)lr * L10K32);
    float f2 = __builtin_amdgcn_exp2f(-(float)(lr + 16) * L10K32);
    {
        float b0 = biasq[hb + lr],      b1 = biasq[hb + 16 + lr];
        float b2 = biasq[hb + 32 + lr], b3 = biasq[hb + 48 + lr];
#pragma unroll
        for (int ms = 0; ms < 4; ms++)
#pragma unroll
        for (int r = 0; r < 4; r++) {
            long row = m0 + wm * 64 + ms * 16 + quad * 4 + r;
            int pos = (int)(row & (SEQ - 1));
            float s1, c1, s2, c2;
            __sincosf((float)pos * f1, &s1, &c1);
            __sincosf((float)pos * f2, &s2, &c2);
            float v0 = accq[ms][0][r] + b0, v1 = accq[ms][1][r] + b1;
            float v2 = accq[ms][2][r] + b2, v3 = accq[ms][3][r] + b3;
            __bf16* ob = outq + row * HID + hb;
            ob[lr]      = (__bf16)((v0 * c1 - v2 * s1) * QSCALE);
            ob[16 + lr] = (__bf16)((v1 * c2 - v3 * s2) * QSCALE);
            ob[32 + lr] = (__bf16)((v2 * c1 + v0 * s1) * QSCALE);
            ob[48 + lr] = (__bf16)((v3 * c2 + v1 * s2) * QSCALE);
        }
    }
    {
        float b0 = biask[hb + lr],      b1 = biask[hb + 16 + lr];
        float b2 = biask[hb + 32 + lr], b3 = biask[hb + 48 + lr];
#pragma unroll
        for (int ms = 0; ms < 4; ms++)
#pragma unroll
        for (int r = 0; r < 4; r++) {
            long row = m0 + wm * 64 + ms * 16 + quad * 4 + r;
            int pos = (int)(row & (SEQ - 1));
            float s1, c1, s2, c2;
            __sincosf((float)pos * f1, &s1, &c1);
            __sincosf((float)pos * f2, &s2, &c2);
            float v0 = acck[ms][0][r] + b0, v1 = acck[ms][1][r] + b1;
            float v2 = acck[ms][2][r] + b2, v3 = acck[ms][3][r] + b3;
            __bf16* ob = outk + row * HID + hb;
            ob[lr]      = (__bf16)(v0 * c1 - v2 * s1);
            ob[16 + lr] = (__bf16)(v1 * c2 - v3 * s2);
            ob[32 + lr] = (__bf16)(v2 * c1 + v0 * s1);
            ob[48 + lr] = (__bf16)(v3 * c2 + v1 * s2);
        }
    }
}

// ---------------------------------------------------------------------------
// Flash attention v8 (unchanged from R8, 144us): 8-wave blocks, flat 48KB
// LDS tri-buffer, per-lane base pointers, 1 barrier/body, counted vmcnt(2),
// no-max exp2 softmax, permlane32_swap P redistribution, o in AGPRs.
// NO min-waves launch bound (R7: forced 40 VGPR -> accumulator spill).
// ---------------------------------------------------------------------------
__global__ __launch_bounds__(512)
void attn_kernel(const __bf16* __restrict__ q, const __bf16* __restrict__ k,
                 const __bf16* __restrict__ vt, __bf16* __restrict__ att) {
    int tid = threadIdx.x, wave = tid >> 6, lane = tid & 63;
    int c = lane & 31, hi = lane >> 5;
    int bb = blockIdx.x;
    int s  = bb & 7;           // sequence -> XCD
    int ii = bb >> 3;          // 0..95
    int h  = ii >> 3;          // head 0..11
    int qt = ii & 7;           // q-super-tile (256 rows), fastest within XCD
    long q0 = (long)s * SEQ + qt * 256 + wave * 32;

    // flat LDS: [0..3*4096) = K bufs 0..2, [12288..) = V bufs 0..2
    __shared__ __align__(16) __bf16 KV[6 * 4096];     // 48KB

    // Q fragments: qf[kk] = Q[q0+c][kk*16 + hi*8 .. +8]  (B-operand layout)
    bf16x8 qf[4];
    {
        const __bf16* qrow = q + (q0 + c) * HID + h * HD + hi * 8;
#pragma unroll
        for (int kk = 0; kk < 4; kk++)
            qf[kk] = *(const bf16x8*)(qrow + kk * 16);
    }

    f32x16 o[2] = {};
    float ls = 0.f;

    const __bf16* kg = k  + (long)s * SEQ * HID + h * HD;
    const __bf16* vg = vt + (long)(s * NH + h) * HD * SEQ;

    int srow = lane >> 3;                 // row within 8-row group (0..7)
    int sgch = (lane & 7) ^ srow;         // swizzled source 16B-chunk

    const __bf16* pb4[4];
#pragma unroll
    for (int kk = 0; kk < 4; kk++)
        pb4[kk] = KV + c * 64 + ((((kk << 1) + hi) ^ (c & 7)) << 3);

#define STAGE(bufi, kv)                                                         \
    {                                                                           \
        gld16(kg + (long)((kv) + wave * 8 + srow) * HID + sgch * 8,             \
              KV + (bufi) * 4096 + wave * 512);                                 \
        gld16(vg + (long)(wave * 8 + srow) * SEQ + (kv) + sgch * 8,             \
              KV + 12288 + (bufi) * 4096 + wave * 512);                         \
    }

#define ATTN_BODY(BUF)                                                          \
    {                                                                           \
        f32x16 st0 = {}, st1 = {};                                              \
        __builtin_amdgcn_s_setprio(1);                                          \
        _Pragma("unroll")                                                       \
        for (int kk = 0; kk < 4; kk++) {                                        \
            bf16x8 kf0 = *(const bf16x8*)(pb4[kk] + (BUF) * 4096);              \
            st0 = MFMA32(kf0, qf[kk], st0);                                     \
            bf16x8 kf1 = *(const bf16x8*)(pb4[kk] + (BUF) * 4096 + 2048);       \
            st1 = MFMA32(kf1, qf[kk], st1);                                     \
        }                                                                       \
        __builtin_amdgcn_s_setprio(0);                                          \
        bf16x8 pb[4];                                                           \
        _Pragma("unroll")                                                       \
        for (int kh = 0; kh < 2; kh++) {                                        \
            unsigned pk[8];                                                     \
            _Pragma("unroll")                                                   \
            for (int i = 0; i < 8; i++) {                                       \
                float e0 = __builtin_amdgcn_exp2f(kh ? st1[2 * i] : st0[2 * i]);        \
                float e1 = __builtin_amdgcn_exp2f(kh ? st1[2 * i + 1] : st0[2 * i + 1]);\
                ls += e0 + e1;                                                  \
                pk[i] = pkbf(e0, e1);                                           \
            }                                                                   \
            _Pragma("unroll")                                                   \
            for (int b = 0; b < 2; b++) {                                       \
                u32x2 r02 = __builtin_amdgcn_permlane32_swap(                   \
                    pk[4 * b + 0], pk[4 * b + 2], false, false);                \
                u32x2 r13 = __builtin_amdgcn_permlane32_swap(                   \
                    pk[4 * b + 1], pk[4 * b + 3], false, false);                \
                union { unsigned u[4]; bf16x8 v; } pu;                          \
                pu.u[0] = r02[0]; pu.u[1] = r13[0];                             \
                pu.u[2] = r02[1]; pu.u[3] = r13[1];                             \
                pb[2 * kh + b] = pu.v;                                          \
            }                                                                   \
        }                                                                       \
        __builtin_amdgcn_s_setprio(1);                                          \
        _Pragma("unroll")                                                       \
        for (int kk = 0; kk < 4; kk++) {                                        \
            bf16x8 vf0 = *(const bf16x8*)(pb4[kk] + 12288 + (BUF) * 4096);      \
            o[0] = MFMA32(vf0, pb[kk], o[0]);                                   \
            bf16x8 vf1 = *(const bf16x8*)(pb4[kk] + 12288 + (BUF) * 4096 + 2048); \
            o[1] = MFMA32(vf1, pb[kk], o[1]);                                   \
        }                                                                       \
        __builtin_amdgcn_s_setprio(0);                                          \
    }

    STAGE(0, 0)
    STAGE(1, 64)              // 4 loads in flight per wave (tiles 0,1)

#pragma unroll 1
    for (int u = 0; u < 10; u++) {
        int kv = u * 3 * 64;
        WAITVN(2); BARR();               // tile 3u landed (all waves)
        STAGE(2, kv + 2 * 64)
        ATTN_BODY(0)
        WAITVN(2); BARR();
        STAGE(0, kv + 3 * 64)
        ATTN_BODY(1)
        WAITVN(2); BARR();
        STAGE(1, kv + 4 * 64)
        ATTN_BODY(2)
    }
    WAITVN(2); BARR();
    ATTN_BODY(0)
    WAITVN(0); BARR();
    ATTN_BODY(1)

#undef STAGE
#undef ATTN_BODY

    // ---- epilogue: combine lane-half sums, normalize, pack, store ----
    ls += __shfl_xor(ls, 32);
    float inv = 1.0f / ls;
    __bf16* ob = att + (q0 + c) * HID + h * HD;
#pragma unroll
    for (int dh = 0; dh < 2; dh++)
#pragma unroll
        for (int a = 0; a < 4; a++) {
            unsigned lo  = pkbf(o[dh][4 * a] * inv,     o[dh][4 * a + 1] * inv);
            unsigned hi2 = pkbf(o[dh][4 * a + 2] * inv, o[dh][4 * a + 3] * inv);
            int d = dh * 32 + a * 8 + hi * 4;
            *(unsigned long long*)&ob[d] =
                ((unsigned long long)hi2 << 32) | lo;
        }
}

// ---------------------------------------------------------------------------
extern "C" void kernel_launch(void* const* d_in, const int* in_sizes, int n_in,
                              void* d_out, int out_size, void* d_ws, size_t ws_size,
                              hipStream_t stream) {
    const float* hs    = (const float*)d_in[0];
    const float* normw = (const float*)d_in[3];
    const float* normb = (const float*)d_in[4];
    const float* Wq = (const float*)d_in[5];
    const float* bq = (const float*)d_in[6];
    const float* Wk = (const float*)d_in[7];
    const float* bk = (const float*)d_in[8];
    const float* Wv = (const float*)d_in[9];
    const float* bv = (const float*)d_in[10];
    const float* Wo = (const float*)d_in[11];
    const float* bo = (const float*)d_in[12];

    __bf16* base = (__bf16*)d_ws;
    __bf16* x   = base;            // SZ
    __bf16* qb  = base + SZ;       // SZ
    __bf16* kb  = base + 2 * SZ;   // SZ
    __bf16* vtb = base + 3 * SZ;   // SZ  ([s][h][d][pos])
    __bf16* att = base + 4 * SZ;   // SZ
    __bf16* wqt = base + 5 * SZ;
    __bf16* wkt = wqt + WELE;
    __bf16* wvt = wkt + WELE;
    __bf16* wot = wvt + WELE;

    wconv_kernel<<<dim3(12, 12, 4), 256, 0, stream>>>(Wq, wqt, Wk, wkt, Wv, wvt, Wo, wot);

    ln_kernel<<<(int)T, 256, 0, stream>>>(hs, normw, normb, x);

    gemm_qk<<<dim3(T / 128, HID / 128), 256, 0, stream>>>(x, wqt, wkt, bq, bk, qb, kb);
    gemm_lds<1><<<dim3(HID / 128, T / 128), 256, 0, stream>>>(wvt, x, bv, vtb, nullptr, nullptr, 1.0f);

    attn_kernel<<<dim3(NH * 8 * 8), 512, 0, stream>>>(qb, kb, vtb, att);

    gemm_lds<2><<<dim3(T / 128, HID / 128), 256, 0, stream>>>(att, wot, bo, nullptr, x, (float*)d_out, 1.0f);
}

// Round 10
// 379.758 us; speedup vs baseline: 2.4085x; 1.0026x over previous
//
#include <hip/hip_runtime.h>

typedef __bf16 bf16x8 __attribute__((ext_vector_type(8)));
typedef float  f32x4  __attribute__((ext_vector_type(4)));
typedef float  f32x16 __attribute__((ext_vector_type(16)));
typedef unsigned u32x2 __attribute__((ext_vector_type(2)));

#define MFMA16(a,b,c) __builtin_amdgcn_mfma_f32_16x16x32_bf16((a),(b),(c),0,0,0)
#define MFMA32(a,b,c) __builtin_amdgcn_mfma_f32_32x32x16_bf16((a),(b),(c),0,0,0)

constexpr int  HID  = 768;
constexpr long T    = 16384;          // NUM_SEQS * SEQ_LEN
constexpr long SZ   = T * HID;        // 12,582,912 elements
constexpr int  SEQ  = 2048;
constexpr int  NH   = 12;
constexpr int  HD   = 64;
constexpr int  WELE = HID * HID;      // 589,824

// Q pre-scale: (1/sqrt(64)) * log2(e)  -> softmax done in exp2 domain
constexpr float QSCALE = 0.125f * 1.4426950408889634f;
// log2(10000)/32 for RoPE inv_freq = 2^(-d * L10K32)
constexpr float L10K32 = 13.287712379549449f / 32.0f;

__device__ __forceinline__ unsigned pkbf(float a, float b) {
    union { __bf16 h[2]; unsigned u; } x;
    x.h[0] = (__bf16)a; x.h[1] = (__bf16)b; return x.u;
}

// async global->LDS, 16B per lane; LDS dest = uniform base + lane*16
__device__ __forceinline__ void gld16(const __bf16* g, __bf16* l) {
    __builtin_amdgcn_global_load_lds(
        (const __attribute__((address_space(1))) unsigned int*)g,
        (__attribute__((address_space(3))) unsigned int*)l, 16, 0, 0);
}

#define WAITVN(N) asm volatile("s_waitcnt vmcnt(" #N ")" ::: "memory")
#define BARR()    asm volatile("s_barrier" ::: "memory")

// ---------------------------------------------------------------------------
// Weight convert+transpose (z<4), LDS-tiled; z==4 fills the RoPE table:
// rope[pos*16+lr] = float4(cos(pos*f1), sin(pos*f1), cos(pos*f2), sin(pos*f2))
// with f1=2^(-lr*L10K32), f2=2^(-(lr+16)*L10K32).  512KB, L2/L3-resident.
// ---------------------------------------------------------------------------
__global__ __launch_bounds__(256)
void wconv_kernel(const float* __restrict__ W0, __bf16* __restrict__ T0,
                  const float* __restrict__ W1, __bf16* __restrict__ T1,
                  const float* __restrict__ W2, __bf16* __restrict__ T2,
                  const float* __restrict__ W3, __bf16* __restrict__ T3,
                  float* __restrict__ rope) {
    if (blockIdx.z == 4) {
        int gid = (blockIdx.y * 12 + blockIdx.x) * 256 + threadIdx.x;
        if (gid < SEQ * 16) {
            int pos = gid >> 4, lr = gid & 15;
            float f1 = __builtin_amdgcn_exp2f(-(float)lr * L10K32);
            float f2 = __builtin_amdgcn_exp2f(-(float)(lr + 16) * L10K32);
            float s1, c1, s2, c2;
            __sincosf((float)pos * f1, &s1, &c1);
            __sincosf((float)pos * f2, &s2, &c2);
            f32x4 v = {c1, s1, c2, s2};
            *(f32x4*)&rope[(long)gid * 4] = v;
        }
        return;
    }
    const float* W; __bf16* Wt;
    switch (blockIdx.z) {
        case 0: W = W0; Wt = T0; break;
        case 1: W = W1; Wt = T1; break;
        case 2: W = W2; Wt = T2; break;
        default: W = W3; Wt = T3; break;
    }
    __shared__ float tile[64][65];
    int n0 = blockIdx.x * 64, k0 = blockIdx.y * 64;
    int c = threadIdx.x & 63, rr = threadIdx.x >> 6;
#pragma unroll
    for (int i = 0; i < 16; i++) {
        int r = i * 4 + rr;
        tile[r][c] = W[(long)(k0 + r) * HID + n0 + c];
    }
    __syncthreads();
#pragma unroll
    for (int i = 0; i < 16; i++) {
        int r = i * 4 + rr;
        Wt[(long)(n0 + r) * HID + k0 + c] = (__bf16)tile[c][r];
    }
}

// ---------------------------------------------------------------------------
// LayerNorm
// ---------------------------------------------------------------------------
__global__ __launch_bounds__(256)
void ln_kernel(const float* __restrict__ hs, const float* __restrict__ w,
               const float* __restrict__ b, __bf16* __restrict__ xbf) {
    int row = blockIdx.x, tid = threadIdx.x;
    const float* hr = hs + (long)row * HID;
    float v0 = hr[tid], v1 = hr[tid + 256], v2 = hr[tid + 512];
    float s  = v0 + v1 + v2;
    float s2 = v0 * v0 + v1 * v1 + v2 * v2;
#pragma unroll
    for (int off = 1; off < 64; off <<= 1) {
        s  += __shfl_xor(s, off);
        s2 += __shfl_xor(s2, off);
    }
    __shared__ float red[8];
    int wave = tid >> 6;
    if ((tid & 63) == 0) { red[wave] = s; red[4 + wave] = s2; }
    __syncthreads();
    s  = red[0] + red[1] + red[2] + red[3];
    s2 = red[4] + red[5] + red[6] + red[7];
    float mu   = s * (1.0f / HID);
    float var  = s2 * (1.0f / HID) - mu * mu;
    float rstd = rsqrtf(var + 1e-12f);
    long base = (long)row * HID;
    xbf[base + tid]       = (__bf16)((v0 - mu) * rstd * w[tid]       + b[tid]);
    xbf[base + tid + 256] = (__bf16)((v1 - mu) * rstd * w[tid + 256] + b[tid + 256]);
    xbf[base + tid + 512] = (__bf16)((v2 - mu) * rstd * w[tid + 512] + b[tid + 512]);
}

// ---------------------------------------------------------------------------
// GEMM v3: qk-style asymmetric pipeline.  The STREAMED operand (unique data
// per block: x for MODE 1, att for MODE 2) is double-buffered with 2-tile
// prefetch depth; the WEIGHT operand (L2-hot) is single-buffered and staged
// right after the post-compute barrier (only ~L2 latency exposed).
// LDS 3 x 16.9KB = 50.7KB -> 3 blocks/CU (was 2).  Per step t:
//   COMP(t) -> BAR -> STAGE_W(t+1), STAGE_S(t+2) -> vmcnt(4) -> BAR
// MODE 1: V proj A=Wv^T [weights], B=x [stream] -> vtb [s][h][d][pos].
// MODE 2: final proj A=att [stream], B=Wo^T [weights]; fp32 + bias + resid.
// ---------------------------------------------------------------------------
constexpr int SEGSZ = 528;   // elements per 8-row segment: 1024B data + 32B pad
constexpr int BUFSZ = 16 * SEGSZ;

template <int MODE>
__global__ __launch_bounds__(256)
void gemm_lds(const __bf16* __restrict__ A, const __bf16* __restrict__ Bt,
              const float* __restrict__ bias, __bf16* __restrict__ outb,
              const __bf16* __restrict__ resid, float* __restrict__ outf,
              float scale) {
    int tid = threadIdx.x, wave = tid >> 6, lane = tid & 63;
    int lr = lane & 15, quad = lane >> 4;
    int wm = wave >> 1, wn = wave & 1;
    long m0 = (long)blockIdx.x * 128;
    int  n0 = blockIdx.y * 128;

    __shared__ __align__(16) __bf16 Ss[2][BUFSZ];   // streamed operand
    __shared__ __align__(16) __bf16 Ws[BUFSZ];      // weight operand

    const f32x4 vzero = {0.f, 0.f, 0.f, 0.f};
    f32x4 acc[4][4];
#pragma unroll
    for (int ms = 0; ms < 4; ms++)
#pragma unroll
        for (int ns = 0; ns < 4; ns++) acc[ms][ns] = vzero;

    const __bf16* ga = A  + (long)(m0 + wave * 32 + (lane >> 3)) * HID + (lane & 7) * 8;
    const __bf16* gb = Bt + (long)(n0 + wave * 32 + (lane >> 3)) * HID + (lane & 7) * 8;
    const __bf16* gs = (MODE == 2) ? ga : gb;   // streamed source
    const __bf16* gw = (MODE == 2) ? gb : ga;   // weight source

    int fbase = (lr >> 3) * SEGSZ + (lr & 7) * 64 + quad * 8;

#define SSTAGE(b, k0)                                                           \
    {                                                                           \
        _Pragma("unroll")                                                       \
        for (int j = 0; j < 4; j++)                                             \
            gld16(gs + (long)j * 8 * HID + (k0), Ss[b] + wave * 4 * SEGSZ + j * SEGSZ); \
    }
#define WSTAGE(k0)                                                              \
    {                                                                           \
        _Pragma("unroll")                                                       \
        for (int j = 0; j < 4; j++)                                             \
            gld16(gw + (long)j * 8 * HID + (k0), Ws + wave * 4 * SEGSZ + j * SEGSZ); \
    }
#define GCOMP(b)                                                                \
    {                                                                           \
        const __bf16* Ab = (MODE == 2) ? &Ss[b][0] : &Ws[0];                    \
        const __bf16* Bb = (MODE == 2) ? &Ws[0] : &Ss[b][0];                    \
        _Pragma("unroll")                                                       \
        for (int kk = 0; kk < 64; kk += 32) {                                   \
            bf16x8 af[4], bfr[4];                                               \
            _Pragma("unroll")                                                   \
            for (int ms = 0; ms < 4; ms++)                                      \
                af[ms] = *(const bf16x8*)&Ab[fbase + (wm * 8 + ms * 2) * SEGSZ + kk]; \
            _Pragma("unroll")                                                   \
            for (int ns = 0; ns < 4; ns++)                                      \
                bfr[ns] = *(const bf16x8*)&Bb[fbase + (wn * 8 + ns * 2) * SEGSZ + kk]; \
            _Pragma("unroll")                                                   \
            for (int ms = 0; ms < 4; ms++)                                      \
                _Pragma("unroll")                                               \
                for (int ns = 0; ns < 4; ns++)                                  \
                    acc[ms][ns] = MFMA16(af[ms], bfr[ns], acc[ms][ns]);         \
        }                                                                       \
    }

    SSTAGE(0, 0) WSTAGE(0) SSTAGE(1, 64)
    WAITVN(4); BARR();          // S0,W0 landed; S1 in flight

#pragma unroll 1
    for (int u = 0; u < 5; u++) {
        int k0 = u * 128;
        GCOMP(0) BARR();
        WSTAGE(k0 + 64)  SSTAGE(0, k0 + 128) WAITVN(4); BARR();
        GCOMP(1) BARR();
        WSTAGE(k0 + 128) SSTAGE(1, k0 + 192) WAITVN(4); BARR();
    }
    GCOMP(0) BARR();
    WSTAGE(11 * 64) WAITVN(0); BARR();
    GCOMP(1)

#undef SSTAGE
#undef WSTAGE
#undef GCOMP

    if (MODE == 1) {
#pragma unroll
        for (int ms = 0; ms < 4; ms++)
#pragma unroll
        for (int r = 0; r < 4; r++) {
            int d = (int)(m0 + wm * 64 + ms * 16 + quad * 4 + r);   // 0..767
            float bv = bias[d];
            int hh = d >> 6, dd = d & 63;
#pragma unroll
            for (int ns = 0; ns < 4; ns++) {
                int posg = n0 + wn * 64 + ns * 16 + lr;
                int sq = posg >> 11, pos = posg & (SEQ - 1);
                outb[((long)((sq * NH + hh) * HD + dd) << 11) + pos] =
                    (__bf16)(acc[ms][ns][r] + bv);
            }
        }
    } else { // MODE 2
#pragma unroll
        for (int ns = 0; ns < 4; ns++) {
            int col = n0 + wn * 64 + ns * 16 + lr;
            float bv = bias[col];
#pragma unroll
            for (int ms = 0; ms < 4; ms++)
#pragma unroll
            for (int r = 0; r < 4; r++) {
                long row = m0 + wm * 64 + ms * 16 + quad * 4 + r;
                outf[row * HID + col] = acc[ms][ns][r] + bv + (float)resid[row * HID + col];
            }
        }
    }
}

// ---------------------------------------------------------------------------
// Fused Q+K projection, 2-phase (unchanged schedule); epilogue now reads the
// precomputed RoPE table (one f32x4 per (ms,r), shared by Q and K) instead of
// computing 64 __sincosf per thread.
// ---------------------------------------------------------------------------
__global__ __launch_bounds__(256, 2)
void gemm_qk(const __bf16* __restrict__ A, const __bf16* __restrict__ Btq,
             const __bf16* __restrict__ Btk,
             const float* __restrict__ biasq, const float* __restrict__ biask,
             __bf16* __restrict__ outq, __bf16* __restrict__ outk,
             const float* __restrict__ rope) {
    int tid = threadIdx.x, wave = tid >> 6, lane = tid & 63;
    int lr = lane & 15, quad = lane >> 4;
    int wm = wave >> 1, wn = wave & 1;
    long m0 = (long)blockIdx.x * 128;
    int  n0 = blockIdx.y * 128;

    __shared__ __align__(16) __bf16 As[2][BUFSZ];
    __shared__ __align__(16) __bf16 Bqs[BUFSZ];
    __shared__ __align__(16) __bf16 Bks[BUFSZ];

    const f32x4 vzero = {0.f, 0.f, 0.f, 0.f};
    f32x4 accq[4][4], acck[4][4];
#pragma unroll
    for (int ms = 0; ms < 4; ms++)
#pragma unroll
        for (int ns = 0; ns < 4; ns++) { accq[ms][ns] = vzero; acck[ms][ns] = vzero; }

    const __bf16* ga = A   + (long)(m0 + wave * 32 + (lane >> 3)) * HID + (lane & 7) * 8;
    const __bf16* gq = Btq + (long)(n0 + wave * 32 + (lane >> 3)) * HID + (lane & 7) * 8;
    const __bf16* gk = Btk + (long)(n0 + wave * 32 + (lane >> 3)) * HID + (lane & 7) * 8;

    int fbase = (lr >> 3) * SEGSZ + (lr & 7) * 64 + quad * 8;

#define QSTAGE_A(b, k0)                                                         \
    {                                                                           \
        _Pragma("unroll")                                                       \
        for (int j = 0; j < 4; j++)                                             \
            gld16(ga + (long)j * 8 * HID + (k0), As[b] + wave * 4 * SEGSZ + j * SEGSZ); \
    }
#define QSTAGE_B(k0)                                                            \
    {                                                                           \
        _Pragma("unroll")                                                       \
        for (int j = 0; j < 4; j++) {                                           \
            gld16(gq + (long)j * 8 * HID + (k0), Bqs + wave * 4 * SEGSZ + j * SEGSZ); \
            gld16(gk + (long)j * 8 * HID + (k0), Bks + wave * 4 * SEGSZ + j * SEGSZ); \
        }                                                                       \
    }
#define QCOMP(b)                                                                \
    {                                                                           \
        _Pragma("unroll")                                                       \
        for (int kk = 0; kk < 64; kk += 32) {                                   \
            bf16x8 af[4], bqf[4], bkf[4];                                       \
            _Pragma("unroll")                                                   \
            for (int ms = 0; ms < 4; ms++)                                      \
                af[ms] = *(const bf16x8*)&As[b][fbase + (wm * 8 + ms * 2) * SEGSZ + kk]; \
            _Pragma("unroll")                                                   \
            for (int ns = 0; ns < 4; ns++) {                                    \
                bqf[ns] = *(const bf16x8*)&Bqs[fbase + (wn * 8 + ns * 2) * SEGSZ + kk]; \
                bkf[ns] = *(const bf16x8*)&Bks[fbase + (wn * 8 + ns * 2) * SEGSZ + kk]; \
            }                                                                   \
            _Pragma("unroll")                                                   \
            for (int ms = 0; ms < 4; ms++)                                      \
                _Pragma("unroll")                                               \
                for (int ns = 0; ns < 4; ns++) {                                \
                    accq[ms][ns] = MFMA16(af[ms], bqf[ns], accq[ms][ns]);       \
                    acck[ms][ns] = MFMA16(af[ms], bkf[ns], acck[ms][ns]);       \
                }                                                               \
        }                                                                       \
    }

    QSTAGE_A(0, 0) QSTAGE_B(0) QSTAGE_A(1, 64)
    WAITVN(4); BARR();          // A0,B0 landed; A1 in flight

#pragma unroll 1
    for (int u = 0; u < 5; u++) {
        int k0 = u * 128;
        QCOMP(0) BARR();
        QSTAGE_B(k0 + 64)  QSTAGE_A(0, k0 + 128) WAITVN(4); BARR();
        QCOMP(1) BARR();
        QSTAGE_B(k0 + 128) QSTAGE_A(1, k0 + 192) WAITVN(4); BARR();
    }
    QCOMP(0) BARR();
    QSTAGE_B(11 * 64) WAITVN(0); BARR();
    QCOMP(1)

#undef QSTAGE_A
#undef QSTAGE_B
#undef QCOMP

    // epilogue: table-based RoPE; Q (scale=QSCALE) and K (scale=1) fused.
    int hb = n0 + wn * 64;
    float q0b = biasq[hb + lr],      q1b = biasq[hb + 16 + lr];
    float q2b = biasq[hb + 32 + lr], q3b = biasq[hb + 48 + lr];
    float k0b = biask[hb + lr],      k1b = biask[hb + 16 + lr];
    float k2b = biask[hb + 32 + lr], k3b = biask[hb + 48 + lr];
#pragma unroll
    for (int ms = 0; ms < 4; ms++)
#pragma unroll
    for (int r = 0; r < 4; r++) {
        long row = m0 + wm * 64 + ms * 16 + quad * 4 + r;
        int pos = (int)(row & (SEQ - 1));
        f32x4 tb = *(const f32x4*)&rope[((long)pos * 16 + lr) * 4];
        float c1 = tb[0], s1 = tb[1], c2 = tb[2], s2 = tb[3];
        {
            float v0 = accq[ms][0][r] + q0b, v1 = accq[ms][1][r] + q1b;
            float v2 = accq[ms][2][r] + q2b, v3 = accq[ms][3][r] + q3b;
            __bf16* ob = outq + row * HID + hb;
            ob[lr]      = (__bf16)((v0 * c1 - v2 * s1) * QSCALE);
            ob[16 + lr] = (__bf16)((v1 * c2 - v3 * s2) * QSCALE);
            ob[32 + lr] = (__bf16)((v2 * c1 + v0 * s1) * QSCALE);
            ob[48 + lr] = (__bf16)((v3 * c2 + v1 * s2) * QSCALE);
        }
        {
            float v0 = acck[ms][0][r] + k0b, v1 = acck[ms][1][r] + k1b;
            float v2 = acck[ms][2][r] + k2b, v3 = acck[ms][3][r] + k3b;
            __bf16* ob = outk + row * HID + hb;
            ob[lr]      = (__bf16)(v0 * c1 - v2 * s1);
            ob[16 + lr] = (__bf16)(v1 * c2 - v3 * s2);
            ob[32 + lr] = (__bf16)(v2 * c1 + v0 * s1);
            ob[48 + lr] = (__bf16)(v3 * c2 + v1 * s2);
        }
    }
}

// ---------------------------------------------------------------------------
// Flash attention v8 (unchanged from R8/R9, 144us): 8-wave blocks, flat 48KB
// LDS tri-buffer, per-lane base pointers, 1 barrier/body, counted vmcnt(2),
// no-max exp2 softmax, permlane32_swap P redistribution, o in AGPRs.
// NO min-waves launch bound (R7: forced 40 VGPR -> accumulator spill).
// ---------------------------------------------------------------------------
__global__ __launch_bounds__(512)
void attn_kernel(const __bf16* __restrict__ q, const __bf16* __restrict__ k,
                 const __bf16* __restrict__ vt, __bf16* __restrict__ att) {
    int tid = threadIdx.x, wave = tid >> 6, lane = tid & 63;
    int c = lane & 31, hi = lane >> 5;
    int bb = blockIdx.x;
    int s  = bb & 7;           // sequence -> XCD
    int ii = bb >> 3;          // 0..95
    int h  = ii >> 3;          // head 0..11
    int qt = ii & 7;           // q-super-tile (256 rows), fastest within XCD
    long q0 = (long)s * SEQ + qt * 256 + wave * 32;

    // flat LDS: [0..3*4096) = K bufs 0..2, [12288..) = V bufs 0..2
    __shared__ __align__(16) __bf16 KV[6 * 4096];     // 48KB

    // Q fragments: qf[kk] = Q[q0+c][kk*16 + hi*8 .. +8]  (B-operand layout)
    bf16x8 qf[4];
    {
        const __bf16* qrow = q + (q0 + c) * HID + h * HD + hi * 8;
#pragma unroll
        for (int kk = 0; kk < 4; kk++)
            qf[kk] = *(const bf16x8*)(qrow + kk * 16);
    }

    f32x16 o[2] = {};
    float ls = 0.f;

    const __bf16* kg = k  + (long)s * SEQ * HID + h * HD;
    const __bf16* vg = vt + (long)(s * NH + h) * HD * SEQ;

    int srow = lane >> 3;                 // row within 8-row group (0..7)
    int sgch = (lane & 7) ^ srow;         // swizzled source 16B-chunk

    const __bf16* pb4[4];
#pragma unroll
    for (int kk = 0; kk < 4; kk++)
        pb4[kk] = KV + c * 64 + ((((kk << 1) + hi) ^ (c & 7)) << 3);

#define STAGE(bufi, kv)                                                         \
    {                                                                           \
        gld16(kg + (long)((kv) + wave * 8 + srow) * HID + sgch * 8,             \
              KV + (bufi) * 4096 + wave * 512);                                 \
        gld16(vg + (long)(wave * 8 + srow) * SEQ + (kv) + sgch * 8,             \
              KV + 12288 + (bufi) * 4096 + wave * 512);                         \
    }

#define ATTN_BODY(BUF)                                                          \
    {                                                                           \
        f32x16 st0 = {}, st1 = {};                                              \
        __builtin_amdgcn_s_setprio(1);                                          \
        _Pragma("unroll")                                                       \
        for (int kk = 0; kk < 4; kk++) {                                        \
            bf16x8 kf0 = *(const bf16x8*)(pb4[kk] + (BUF) * 4096);              \
            st0 = MFMA32(kf0, qf[kk], st0);                                     \
            bf16x8 kf1 = *(const bf16x8*)(pb4[kk] + (BUF) * 4096 + 2048);       \
            st1 = MFMA32(kf1, qf[kk], st1);                                     \
        }                                                                       \
        __builtin_amdgcn_s_setprio(0);                                          \
        bf16x8 pb[4];                                                           \
        _Pragma("unroll")                                                       \
        for (int kh = 0; kh < 2; kh++) {                                        \
            unsigned pk[8];                                                     \
            _Pragma("unroll")                                                   \
            for (int i = 0; i < 8; i++) {                                       \
                float e0 = __builtin_amdgcn_exp2f(kh ? st1[2 * i] : st0[2 * i]);        \
                float e1 = __builtin_amdgcn_exp2f(kh ? st1[2 * i + 1] : st0[2 * i + 1]);\
                ls += e0 + e1;                                                  \
                pk[i] = pkbf(e0, e1);                                           \
            }                                                                   \
            _Pragma("unroll")                                                   \
            for (int b = 0; b < 2; b++) {                                       \
                u32x2 r02 = __builtin_amdgcn_permlane32_swap(                   \
                    pk[4 * b + 0], pk[4 * b + 2], false, false);                \
                u32x2 r13 = __builtin_amdgcn_permlane32_swap(                   \
                    pk[4 * b + 1], pk[4 * b + 3], false, false);                \
                union { unsigned u[4]; bf16x8 v; } pu;                          \
                pu.u[0] = r02[0]; pu.u[1] = r13[0];                             \
                pu.u[2] = r02[1]; pu.u[3] = r13[1];                             \
                pb[2 * kh + b] = pu.v;                                          \
            }                                                                   \
        }                                                                       \
        __builtin_amdgcn_s_setprio(1);                                          \
        _Pragma("unroll")                                                       \
        for (int kk = 0; kk < 4; kk++) {                                        \
            bf16x8 vf0 = *(const bf16x8*)(pb4[kk] + 12288 + (BUF) * 4096);      \
            o[0] = MFMA32(vf0, pb[kk], o[0]);                                   \
            bf16x8 vf1 = *(const bf16x8*)(pb4[kk] + 12288 + (BUF) * 4096 + 2048); \
            o[1] = MFMA32(vf1, pb[kk], o[1]);                                   \
        }                                                                       \
        __builtin_amdgcn_s_setprio(0);                                          \
    }

    STAGE(0, 0)
    STAGE(1, 64)              // 4 loads in flight per wave (tiles 0,1)

#pragma unroll 1
    for (int u = 0; u < 10; u++) {
        int kv = u * 3 * 64;
        WAITVN(2); BARR();               // tile 3u landed (all waves)
        STAGE(2, kv + 2 * 64)
        ATTN_BODY(0)
        WAITVN(2); BARR();
        STAGE(0, kv + 3 * 64)
        ATTN_BODY(1)
        WAITVN(2); BARR();
        STAGE(1, kv + 4 * 64)
        ATTN_BODY(2)
    }
    WAITVN(2); BARR();
    ATTN_BODY(0)
    WAITVN(0); BARR();
    ATTN_BODY(1)

#undef STAGE
#undef ATTN_BODY

    // ---- epilogue: combine lane-half sums, normalize, pack, store ----
    ls += __shfl_xor(ls, 32);
    float inv = 1.0f / ls;
    __bf16* ob = att + (q0 + c) * HID + h * HD;
#pragma unroll
    for (int dh = 0; dh < 2; dh++)
#pragma unroll
        for (int a = 0; a < 4; a++) {
            unsigned lo  = pkbf(o[dh][4 * a] * inv,     o[dh][4 * a + 1] * inv);
            unsigned hi2 = pkbf(o[dh][4 * a + 2] * inv, o[dh][4 * a + 3] * inv);
            int d = dh * 32 + a * 8 + hi * 4;
            *(unsigned long long*)&ob[d] =
                ((unsigned long long)hi2 << 32) | lo;
        }
}

// ---------------------------------------------------------------------------
extern "C" void kernel_launch(void* const* d_in, const int* in_sizes, int n_in,
                              void* d_out, int out_size, void* d_ws, size_t ws_size,
                              hipStream_t stream) {
    const float* hs    = (const float*)d_in[0];
    const float* normw = (const float*)d_in[3];
    const float* normb = (const float*)d_in[4];
    const float* Wq = (const float*)d_in[5];
    const float* bq = (const float*)d_in[6];
    const float* Wk = (const float*)d_in[7];
    const float* bk = (const float*)d_in[8];
    const float* Wv = (const float*)d_in[9];
    const float* bv = (const float*)d_in[10];
    const float* Wo = (const float*)d_in[11];
    const float* bo = (const float*)d_in[12];

    __bf16* base = (__bf16*)d_ws;
    __bf16* x   = base;            // SZ
    __bf16* qb  = base + SZ;       // SZ
    __bf16* kb  = base + 2 * SZ;   // SZ
    __bf16* vtb = base + 3 * SZ;   // SZ  ([s][h][d][pos])
    __bf16* att = base + 4 * SZ;   // SZ
    __bf16* wqt = base + 5 * SZ;
    __bf16* wkt = wqt + WELE;
    __bf16* wvt = wkt + WELE;
    __bf16* wot = wvt + WELE;
    float*  rope = (float*)(wot + WELE);   // 2048*16 float4 = 512KB (16B-aligned)

    wconv_kernel<<<dim3(12, 12, 5), 256, 0, stream>>>(Wq, wqt, Wk, wkt, Wv, wvt, Wo, wot, rope);

    ln_kernel<<<(int)T, 256, 0, stream>>>(hs, normw, normb, x);

    gemm_qk<<<dim3(T / 128, HID / 128), 256, 0, stream>>>(x, wqt, wkt, bq, bk, qb, kb, rope);
    gemm_lds<1><<<dim3(HID / 128, T / 128), 256, 0, stream>>>(wvt, x, bv, vtb, nullptr, nullptr, 1.0f);

    attn_kernel<<<dim3(NH * 8 * 8), 512, 0, stream>>>(qb, kb, vtb, att);

    gemm_lds<2><<<dim3(T / 128, HID / 128), 256, 0, stream>>>(att, wot, bo, nullptr, x, (float*)d_out, 1.0f);
}